// Round 2
// baseline (673.146 us; speedup 1.0000x reference)
//
#include <hip/hip_runtime.h>
#include <hip/hip_bf16.h>
#include <cstdint>

// Qwen3-VL-MoE text experts: permute -> grouped GEMM (gate_up) -> SwiGLU ->
// grouped GEMM (down) -> unpermute+combine.  bf16 MFMA path.
// R2: 256x256 tile, BK=32, 3-buffer LDS ring, counted vmcnt (never 0 in
// steady state), raw s_barrier (1 per K-tile), setprio around MFMA clusters,
// swizzled LDS reads via pre-swizzled global_load_lds sources.

#define E_   32
#define H_   2048
#define D_   768
#define T_   4096
#define K_   8
#define M_   (T_ * K_)   // 32768 expanded rows
#define G_   (M_ / E_)   // 1024 rows per expert (balanced)
#define GU2  (2 * D_)    // 1536

typedef unsigned short u16;
typedef short bf16x8 __attribute__((ext_vector_type(8)));
typedef float f32x4 __attribute__((ext_vector_type(4)));
typedef unsigned short u16x2 __attribute__((ext_vector_type(2)));
typedef unsigned short u16x8 __attribute__((ext_vector_type(8)));

__device__ __forceinline__ u16 f2bf(float f) {          // RNE f32 -> bf16
  unsigned u = __float_as_uint(f);
  u += 0x7FFFu + ((u >> 16) & 1u);
  return (u16)(u >> 16);
}
__device__ __forceinline__ float bf2f(u16 v) {
  return __uint_as_float(((unsigned)v) << 16);
}

#define GLOAD16(g, l) __builtin_amdgcn_global_load_lds(                        \
    (const __attribute__((address_space(1))) void*)(g),                        \
    (__attribute__((address_space(3))) void*)(l), 16, 0, 0)

#define WAITVM4() asm volatile("s_waitcnt vmcnt(4)" ::: "memory")
#define WAITVM0() asm volatile("s_waitcnt vmcnt(0)" ::: "memory")

// ---------------------------------------------------------------- prep ------
__global__ __launch_bounds__(256) void cvt_hidden(const float* __restrict__ in,
                                                  u16* __restrict__ out) {
  const int i = blockIdx.x * 256 + threadIdx.x;       // float4 groups
  const float4 v = ((const float4*)in)[i];
  u16x2 a; a.x = f2bf(v.x); a.y = f2bf(v.y);
  u16x2 b; b.x = f2bf(v.z); b.y = f2bf(v.w);
  *(u16x2*)&out[(size_t)i * 4]     = a;
  *(u16x2*)&out[(size_t)i * 4 + 2] = b;
}

// in: (B, R, C) f32  ->  out: (B, C, R) bf16, with optional gate/up
// 16-column interleave remap of the output row (mode 1: C==1536,
// gate j -> (j>>4)*32 + (j&15), up j -> (j>>4)*32 + 16 + (j&15)).
__global__ __launch_bounds__(256) void transpose_cvt(const float* __restrict__ in,
                                                     u16* __restrict__ out,
                                                     int R, int C, int mode) {
  __shared__ u16 tl[64][65];
  const int b = blockIdx.z;
  const int c0 = blockIdx.x * 64, r0 = blockIdx.y * 64;
  const float* ip = in + ((size_t)b * R + r0) * C + c0;
  const int lr = threadIdx.x >> 6;   // 0..3
  const int lc = threadIdx.x & 63;
#pragma unroll
  for (int p = 0; p < 16; ++p) {
    const int r = p * 4 + lr;
    tl[r][lc] = f2bf(ip[(size_t)r * C + lc]);
  }
  __syncthreads();
  const int wr = threadIdx.x >> 5;   // 0..7
  const int wi = threadIdx.x & 31;
#pragma unroll
  for (int p = 0; p < 8; ++p) {
    const int c = p * 8 + wr;
    const int gc = c0 + c;
    int rr;
    if (mode == 1) {
      const int j = (gc < D_) ? gc : (gc - D_);
      rr = (j >> 4) * 32 + ((gc < D_) ? 0 : 16) + (j & 15);
    } else {
      rr = gc;
    }
    u16x2 v; v.x = tl[2 * wi][c]; v.y = tl[2 * wi + 1][c];
    *(u16x2*)&out[((size_t)b * C + rr) * R + r0 + 2 * wi] = v;
  }
}

// ------------------------------------------------------------- routing -----
// Stable counting sort by expert id; balanced groups => base[e] = e*G_.
__global__ __launch_bounds__(256) void build_perm(const int* __restrict__ ridx,
                                                  int* __restrict__ perm_src) {
  const int e = blockIdx.x;
  const int lane = threadIdx.x & 63, wid = threadIdx.x >> 6;
  __shared__ int wcnt[4];
  __shared__ int running;
  if (threadIdx.x == 0) running = 0;
  __syncthreads();
  for (int base = 0; base < M_; base += 256) {
    const int i = base + threadIdx.x;
    const bool match = (ridx[i] == e);
    const unsigned long long mask = __ballot(match);
    if (lane == 0) wcnt[wid] = __popcll(mask);
    __syncthreads();
    int wpre = 0;
    for (int w0 = 0; w0 < wid; ++w0) wpre += wcnt[w0];
    const int rank = __popcll(mask & ((1ull << lane) - 1ull));
    if (match) perm_src[e * G_ + running + wpre + rank] = i;
    __syncthreads();
    if (threadIdx.x == 0) running += wcnt[0] + wcnt[1] + wcnt[2] + wcnt[3];
    __syncthreads();
  }
}

__global__ __launch_bounds__(256) void gather_probs(const int* __restrict__ ridx,
                                                    const float* __restrict__ rw,
                                                    float* __restrict__ probs) {
  const int i = blockIdx.x * 256 + threadIdx.x;   // i < M_
  const int t = i >> 3;
  probs[i] = rw[t * E_ + ridx[i]];
}

// --------------------------------------------------------------- GEMM1 -----
// C tile 256x256 stored cols (= 128 D-cols of paired gate/up 16-blocks).
// BK=32, 3-buffer ring, 8 waves (2M x 4N), per-wave 128x64.
__global__ __launch_bounds__(512, 2) void gemm1_swiglu(
    const u16* __restrict__ hid, const u16* __restrict__ gup,
    const int* __restrict__ perm, u16* __restrict__ act) {
  __shared__ u16 As[3][256 * 32];   // 3 x 16 KiB
  __shared__ u16 Bs[3][256 * 32];   // 3 x 16 KiB   (total 96 KiB)
  const int NT = H_ / 32;           // 64 K-tiles

  const int nwg = 6 * 4 * E_;       // 768, %8==0
  const int wid = (blockIdx.x % 8) * (nwg / 8) + blockIdx.x / 8;
  const int e = wid / 24;
  const int mb = (wid / 6) % 4;
  const int nb = wid % 6;

  const int tid = threadIdx.x;
  const int lane = tid & 63, w = tid >> 6;
  const int wr = w >> 2, wc = w & 3;           // 2 x 4 wave grid
  const int sdst = w * 512;                    // per-wave uniform LDS base (u16)

  // staging: thread covers row (tid>>2) of a 128-row half, 16B chunk (tid&3),
  // source chunk pre-swizzled so LDS reads below are ~conflict-free.
  const int srow = tid >> 2, schunk = tid & 3;
  const u16* pA[2]; const u16* pB[2];
#pragma unroll
  for (int h = 0; h < 2; ++h) {
    const int r = h * 128 + srow;
    const int token = perm[e * G_ + mb * 256 + r] >> 3;
    const int kswz = (schunk ^ ((r >> 1) & 3)) * 8;
    pA[h] = hid + (size_t)token * H_ + kswz;
    pB[h] = gup + ((size_t)e * GU2 + nb * 256 + r) * H_ + kswz;
  }

  // ds-read offsets (u16 elems), swizzle matches the staging pre-swizzle
  const int ca = lane >> 4;
  const int rA = wr * 128 + (lane & 15);
  const int rB = wc * 64 + (lane & 15);
  const int aoff0 = rA * 32 + ((ca ^ ((rA >> 1) & 3)) * 8);
  const int boff0 = rB * 32 + ((ca ^ ((rB >> 1) & 3)) * 8);

  f32x4 acc[8][4];
#pragma unroll
  for (int m = 0; m < 8; ++m)
#pragma unroll
    for (int n = 0; n < 4; ++n) acc[m][n] = (f32x4){0.f, 0.f, 0.f, 0.f};

  // prologue: stage tiles 0,1
#pragma unroll
  for (int h = 0; h < 2; ++h) GLOAD16(pA[h], &As[0][h * 4096 + sdst]);
#pragma unroll
  for (int h = 0; h < 2; ++h) GLOAD16(pB[h], &Bs[0][h * 4096 + sdst]);
#pragma unroll
  for (int h = 0; h < 2; ++h) GLOAD16(pA[h] + 32, &As[1][h * 4096 + sdst]);
#pragma unroll
  for (int h = 0; h < 2; ++h) GLOAD16(pB[h] + 32, &Bs[1][h * 4096 + sdst]);
  WAITVM4();                        // tile 0 landed (tile 1 in flight)
  __builtin_amdgcn_s_barrier();
  __builtin_amdgcn_sched_barrier(0);

  int cur = 0;
#pragma unroll 1
  for (int t = 0; t < NT; ++t) {
    const int t2 = t + 2;
    int nxt = cur + 2; if (nxt >= 3) nxt -= 3;
    const u16* Ab = As[cur]; const u16* Bb = Bs[cur];
    // ---- phase A: stage A(t+2), read b[0..3]+a[0..3], 16 MFMA
    if (t2 < NT) {
      GLOAD16(pA[0] + t2 * 32, &As[nxt][sdst]);
      GLOAD16(pA[1] + t2 * 32, &As[nxt][4096 + sdst]);
    }
    bf16x8 b[4], a[4];
#pragma unroll
    for (int n = 0; n < 4; ++n) b[n] = *(const bf16x8*)&Bb[boff0 + n * 512];
#pragma unroll
    for (int m = 0; m < 4; ++m) a[m] = *(const bf16x8*)&Ab[aoff0 + m * 512];
    __builtin_amdgcn_s_setprio(1);
#pragma unroll
    for (int m = 0; m < 4; ++m)
#pragma unroll
      for (int n = 0; n < 4; ++n)
        acc[m][n] = __builtin_amdgcn_mfma_f32_16x16x32_bf16(a[m], b[n],
                                                            acc[m][n], 0, 0, 0);
    __builtin_amdgcn_s_setprio(0);
    // ---- phase B: stage B(t+2), read a[4..7], 16 MFMA
    if (t2 < NT) {
      GLOAD16(pB[0] + t2 * 32, &Bs[nxt][sdst]);
      GLOAD16(pB[1] + t2 * 32, &Bs[nxt][4096 + sdst]);
    }
#pragma unroll
    for (int m = 0; m < 4; ++m)
      a[m] = *(const bf16x8*)&Ab[aoff0 + (m + 4) * 512];
    __builtin_amdgcn_s_setprio(1);
#pragma unroll
    for (int m = 0; m < 4; ++m)
#pragma unroll
      for (int n = 0; n < 4; ++n)
        acc[m + 4][n] = __builtin_amdgcn_mfma_f32_16x16x32_bf16(a[m], b[n],
                                                                acc[m + 4][n], 0, 0, 0);
    __builtin_amdgcn_s_setprio(0);
    // ---- tile boundary: tile t+1 must be landed; t+2's 4 loads stay in flight
    if (t2 < NT) { WAITVM4(); } else { WAITVM0(); }
    __builtin_amdgcn_s_barrier();
    __builtin_amdgcn_sched_barrier(0);
    cur = (cur + 1 == 3) ? 0 : cur + 1;
  }

  // epilogue: SwiGLU on paired (gate,up) fragments, store bf16 act
  const int lrow = (lane >> 4) * 4, lcol = lane & 15;
#pragma unroll
  for (int m = 0; m < 8; ++m)
#pragma unroll
    for (int p = 0; p < 2; ++p)
#pragma unroll
      for (int r = 0; r < 4; ++r) {
        const float g = acc[m][2 * p][r];
        const float u = acc[m][2 * p + 1][r];
        const float a_ = g / (1.f + __expf(-g)) * u;     // silu(g)*u
        const int row = mb * 256 + wr * 128 + m * 16 + lrow + r;
        const int dcol = (nb * 8 + wc * 2 + p) * 16 + lcol;
        act[((size_t)e * G_ + row) * D_ + dcol] = f2bf(a_);
      }
}

// --------------------------------------------------------------- GEMM2 -----
// C tile 256x256, BK=32, K=768; epilogue scatters rows to expanded order.
__global__ __launch_bounds__(512, 2) void gemm2_scatter(
    const u16* __restrict__ act, const u16* __restrict__ dwn,
    const int* __restrict__ perm, u16* __restrict__ expo) {
  __shared__ u16 As[3][256 * 32];
  __shared__ u16 Bs[3][256 * 32];
  const int NT = D_ / 32;           // 24 K-tiles

  const int nwg = 8 * 4 * E_;       // 1024, %8==0
  const int wid = (blockIdx.x % 8) * (nwg / 8) + blockIdx.x / 8;
  const int e = wid / 32;
  const int mb = (wid / 8) % 4;
  const int nb = wid % 8;

  const int tid = threadIdx.x;
  const int lane = tid & 63, w = tid >> 6;
  const int wr = w >> 2, wc = w & 3;
  const int sdst = w * 512;

  const int srow = tid >> 2, schunk = tid & 3;
  const u16* pA[2]; const u16* pB[2];
#pragma unroll
  for (int h = 0; h < 2; ++h) {
    const int r = h * 128 + srow;
    const int kswz = (schunk ^ ((r >> 1) & 3)) * 8;
    pA[h] = act + ((size_t)e * G_ + mb * 256 + r) * D_ + kswz;
    pB[h] = dwn + ((size_t)e * H_ + nb * 256 + r) * D_ + kswz;
  }

  const int ca = lane >> 4;
  const int rA = wr * 128 + (lane & 15);
  const int rB = wc * 64 + (lane & 15);
  const int aoff0 = rA * 32 + ((ca ^ ((rA >> 1) & 3)) * 8);
  const int boff0 = rB * 32 + ((ca ^ ((rB >> 1) & 3)) * 8);

  f32x4 acc[8][4];
#pragma unroll
  for (int m = 0; m < 8; ++m)
#pragma unroll
    for (int n = 0; n < 4; ++n) acc[m][n] = (f32x4){0.f, 0.f, 0.f, 0.f};

#pragma unroll
  for (int h = 0; h < 2; ++h) GLOAD16(pA[h], &As[0][h * 4096 + sdst]);
#pragma unroll
  for (int h = 0; h < 2; ++h) GLOAD16(pB[h], &Bs[0][h * 4096 + sdst]);
#pragma unroll
  for (int h = 0; h < 2; ++h) GLOAD16(pA[h] + 32, &As[1][h * 4096 + sdst]);
#pragma unroll
  for (int h = 0; h < 2; ++h) GLOAD16(pB[h] + 32, &Bs[1][h * 4096 + sdst]);
  WAITVM4();
  __builtin_amdgcn_s_barrier();
  __builtin_amdgcn_sched_barrier(0);

  int cur = 0;
#pragma unroll 1
  for (int t = 0; t < NT; ++t) {
    const int t2 = t + 2;
    int nxt = cur + 2; if (nxt >= 3) nxt -= 3;
    const u16* Ab = As[cur]; const u16* Bb = Bs[cur];
    if (t2 < NT) {
      GLOAD16(pA[0] + t2 * 32, &As[nxt][sdst]);
      GLOAD16(pA[1] + t2 * 32, &As[nxt][4096 + sdst]);
    }
    bf16x8 b[4], a[4];
#pragma unroll
    for (int n = 0; n < 4; ++n) b[n] = *(const bf16x8*)&Bb[boff0 + n * 512];
#pragma unroll
    for (int m = 0; m < 4; ++m) a[m] = *(const bf16x8*)&Ab[aoff0 + m * 512];
    __builtin_amdgcn_s_setprio(1);
#pragma unroll
    for (int m = 0; m < 4; ++m)
#pragma unroll
      for (int n = 0; n < 4; ++n)
        acc[m][n] = __builtin_amdgcn_mfma_f32_16x16x32_bf16(a[m], b[n],
                                                            acc[m][n], 0, 0, 0);
    __builtin_amdgcn_s_setprio(0);
    if (t2 < NT) {
      GLOAD16(pB[0] + t2 * 32, &Bs[nxt][sdst]);
      GLOAD16(pB[1] + t2 * 32, &Bs[nxt][4096 + sdst]);
    }
#pragma unroll
    for (int m = 0; m < 4; ++m)
      a[m] = *(const bf16x8*)&Ab[aoff0 + (m + 4) * 512];
    __builtin_amdgcn_s_setprio(1);
#pragma unroll
    for (int m = 0; m < 4; ++m)
#pragma unroll
      for (int n = 0; n < 4; ++n)
        acc[m + 4][n] = __builtin_amdgcn_mfma_f32_16x16x32_bf16(a[m], b[n],
                                                                acc[m + 4][n], 0, 0, 0);
    __builtin_amdgcn_s_setprio(0);
    if (t2 < NT) { WAITVM4(); } else { WAITVM0(); }
    __builtin_amdgcn_s_barrier();
    __builtin_amdgcn_sched_barrier(0);
    cur = (cur + 1 == 3) ? 0 : cur + 1;
  }

  const int lrow = (lane >> 4) * 4, lcol = lane & 15;
#pragma unroll
  for (int m = 0; m < 8; ++m)
#pragma unroll
    for (int r = 0; r < 4; ++r) {
      const int dst = e * G_ + mb * 256 + wr * 128 + m * 16 + lrow + r;
      const int src = perm[dst];                 // expanded index t*K+k
      u16* orow = expo + (size_t)src * H_ + nb * 256 + wc * 64;
#pragma unroll
      for (int n = 0; n < 4; ++n)
        orow[n * 16 + lcol] = f2bf(acc[m][n][r]);
    }
}

// ------------------------------------------------------------- combine -----
__global__ __launch_bounds__(256) void combine(const u16* __restrict__ expo,
                                               const float* __restrict__ probs,
                                               float* __restrict__ out) {
  const int t = blockIdx.x;
  const int h0 = threadIdx.x * 8;
  float r[8] = {0.f, 0.f, 0.f, 0.f, 0.f, 0.f, 0.f, 0.f};
#pragma unroll
  for (int k = 0; k < K_; ++k) {
    const float p = probs[t * K_ + k];
    const u16x8 v = *(const u16x8*)&expo[((size_t)(t * K_ + k)) * H_ + h0];
#pragma unroll
    for (int j = 0; j < 8; ++j) r[j] += p * bf2f(v[j]);
  }
  float4 o0 = {r[0], r[1], r[2], r[3]};
  float4 o1 = {r[4], r[5], r[6], r[7]};
  *(float4*)&out[(size_t)t * H_ + h0]     = o0;
  *(float4*)&out[(size_t)t * H_ + h0 + 4] = o1;
}

// -------------------------------------------------------------- launch -----
extern "C" void kernel_launch(void* const* d_in, const int* in_sizes, int n_in,
                              void* d_out, int out_size, void* d_ws, size_t ws_size,
                              hipStream_t stream) {
  const float* hidden = (const float*)d_in[0];   // (T, H) f32
  const float* rw     = (const float*)d_in[1];   // (T, E) f32
  const int*   ridx   = (const int*)d_in[2];     // (T, K) i32
  const float* gup_f  = (const float*)d_in[3];   // (E, H, 2D) f32
  const float* dwn_f  = (const float*)d_in[4];   // (E, D, H) f32
  float* out = (float*)d_out;                    // (T, H) f32

  char* ws = (char*)d_ws;
  size_t off = 0;
  auto alloc = [&](size_t bytes) -> void* {
    void* p = ws + off;
    off += (bytes + 255) & ~(size_t)255;
    return p;
  };
  u16*   hid_bf = (u16*)alloc((size_t)T_ * H_ * 2);        //  16.8 MB
  u16*   gup_t  = (u16*)alloc((size_t)E_ * GU2 * H_ * 2);  // 201.3 MB (E,1536i,H)
  u16*   dwn_t  = (u16*)alloc((size_t)E_ * H_ * D_ * 2);   // 100.7 MB (E,H,D)
  u16*   act    = (u16*)alloc((size_t)M_ * D_ * 2);        //  50.3 MB
  u16*   expo   = (u16*)alloc((size_t)M_ * H_ * 2);        // 134.2 MB
  int*   perm   = (int*)alloc((size_t)M_ * 4);
  float* probs  = (float*)alloc((size_t)M_ * 4);
  if (off > ws_size) return;   // workspace too small -> clean fail

  cvt_hidden<<<(T_ * H_ / 4) / 256, 256, 0, stream>>>(hidden, hid_bf);
  transpose_cvt<<<dim3(GU2 / 64, H_ / 64, E_), 256, 0, stream>>>(gup_f, gup_t, H_, GU2, 1);
  transpose_cvt<<<dim3(H_ / 64, D_ / 64, E_), 256, 0, stream>>>(dwn_f, dwn_t, D_, H_, 0);
  build_perm<<<E_, 256, 0, stream>>>(ridx, perm);
  gather_probs<<<M_ / 256, 256, 0, stream>>>(ridx, rw, probs);
  gemm1_swiglu<<<6 * 4 * E_, 512, 0, stream>>>(hid_bf, gup_t, perm, act);
  gemm2_scatter<<<8 * 4 * E_, 512, 0, stream>>>(act, dwn_t, perm, expo);
  combine<<<T_, 256, 0, stream>>>(expo, probs, out);
}

// Round 3
// 620.047 us; speedup vs baseline: 1.0856x; 1.0856x over previous
//
#include <hip/hip_runtime.h>
#include <hip/hip_bf16.h>
#include <cstdint>

// Qwen3-VL-MoE text experts: permute -> grouped GEMM (gate_up) -> SwiGLU ->
// grouped GEMM (down) -> unpermute+combine.  bf16 MFMA path.
// R3: 256x256 tile, BK=32, 4-slot LDS ring (128 KiB), stage 2 K-tiles ahead,
// 2 phases per K-tile with per-phase barrier pairs (T3), counted vmcnt(4)
// at tile boundaries (T4), setprio around MFMA clusters (T5), conflict-free
// swizzled ds_reads via pre-swizzled global sources (T2), XCD swizzle (T1).

#define E_   32
#define H_   2048
#define D_   768
#define T_   4096
#define K_   8
#define M_   (T_ * K_)   // 32768 expanded rows
#define G_   (M_ / E_)   // 1024 rows per expert (balanced)
#define GU2  (2 * D_)    // 1536

typedef unsigned short u16;
typedef short bf16x8 __attribute__((ext_vector_type(8)));
typedef float f32x4 __attribute__((ext_vector_type(4)));
typedef unsigned short u16x2 __attribute__((ext_vector_type(2)));
typedef unsigned short u16x8 __attribute__((ext_vector_type(8)));

__device__ __forceinline__ u16 f2bf(float f) {          // RNE f32 -> bf16
  unsigned u = __float_as_uint(f);
  u += 0x7FFFu + ((u >> 16) & 1u);
  return (u16)(u >> 16);
}
__device__ __forceinline__ float bf2f(u16 v) {
  return __uint_as_float(((unsigned)v) << 16);
}

#define GLOAD16(g, l) __builtin_amdgcn_global_load_lds(                        \
    (const __attribute__((address_space(1))) void*)(g),                        \
    (__attribute__((address_space(3))) void*)(l), 16, 0, 0)

#define VM4()   asm volatile("s_waitcnt vmcnt(4)" ::: "memory")
#define VM0()   asm volatile("s_waitcnt vmcnt(0)" ::: "memory")
#define LGKM0() asm volatile("s_waitcnt lgkmcnt(0)" ::: "memory")
#define SCHB()  __builtin_amdgcn_sched_barrier(0)
#define BAR()   __builtin_amdgcn_s_barrier()

// ---------------------------------------------------------------- prep ------
__global__ __launch_bounds__(256) void cvt_hidden(const float* __restrict__ in,
                                                  u16* __restrict__ out) {
  const int i = blockIdx.x * 256 + threadIdx.x;       // float4 groups
  const float4 v = ((const float4*)in)[i];
  u16x2 a; a.x = f2bf(v.x); a.y = f2bf(v.y);
  u16x2 b; b.x = f2bf(v.z); b.y = f2bf(v.w);
  *(u16x2*)&out[(size_t)i * 4]     = a;
  *(u16x2*)&out[(size_t)i * 4 + 2] = b;
}

// in: (B, R, C) f32  ->  out: (B, C, R) bf16, with optional gate/up
// 16-column interleave remap of the output row (mode 1: C==1536,
// gate j -> (j>>4)*32 + (j&15), up j -> (j>>4)*32 + 16 + (j&15)).
__global__ __launch_bounds__(256) void transpose_cvt(const float* __restrict__ in,
                                                     u16* __restrict__ out,
                                                     int R, int C, int mode) {
  __shared__ u16 tl[64][65];
  const int b = blockIdx.z;
  const int c0 = blockIdx.x * 64, r0 = blockIdx.y * 64;
  const float* ip = in + ((size_t)b * R + r0) * C + c0;
  const int lr = threadIdx.x >> 6;   // 0..3
  const int lc = threadIdx.x & 63;
#pragma unroll
  for (int p = 0; p < 16; ++p) {
    const int r = p * 4 + lr;
    tl[r][lc] = f2bf(ip[(size_t)r * C + lc]);
  }
  __syncthreads();
  const int wr = threadIdx.x >> 5;   // 0..7
  const int wi = threadIdx.x & 31;
#pragma unroll
  for (int p = 0; p < 8; ++p) {
    const int c = p * 8 + wr;
    const int gc = c0 + c;
    int rr;
    if (mode == 1) {
      const int j = (gc < D_) ? gc : (gc - D_);
      rr = (j >> 4) * 32 + ((gc < D_) ? 0 : 16) + (j & 15);
    } else {
      rr = gc;
    }
    u16x2 v; v.x = tl[2 * wi][c]; v.y = tl[2 * wi + 1][c];
    *(u16x2*)&out[((size_t)b * C + rr) * R + r0 + 2 * wi] = v;
  }
}

// ------------------------------------------------------------- routing -----
// Stable counting sort by expert id; balanced groups => base[e] = e*G_.
__global__ __launch_bounds__(256) void build_perm(const int* __restrict__ ridx,
                                                  int* __restrict__ perm_src) {
  const int e = blockIdx.x;
  const int lane = threadIdx.x & 63, wid = threadIdx.x >> 6;
  __shared__ int wcnt[4];
  __shared__ int running;
  if (threadIdx.x == 0) running = 0;
  __syncthreads();
  for (int base = 0; base < M_; base += 256) {
    const int i = base + threadIdx.x;
    const bool match = (ridx[i] == e);
    const unsigned long long mask = __ballot(match);
    if (lane == 0) wcnt[wid] = __popcll(mask);
    __syncthreads();
    int wpre = 0;
    for (int w0 = 0; w0 < wid; ++w0) wpre += wcnt[w0];
    const int rank = __popcll(mask & ((1ull << lane) - 1ull));
    if (match) perm_src[e * G_ + running + wpre + rank] = i;
    __syncthreads();
    if (threadIdx.x == 0) running += wcnt[0] + wcnt[1] + wcnt[2] + wcnt[3];
    __syncthreads();
  }
}

__global__ __launch_bounds__(256) void gather_probs(const int* __restrict__ ridx,
                                                    const float* __restrict__ rw,
                                                    float* __restrict__ probs) {
  const int i = blockIdx.x * 256 + threadIdx.x;   // i < M_
  const int t = i >> 3;
  probs[i] = rw[t * E_ + ridx[i]];
}

// --------------------------------------------------------------- GEMM1 -----
// 256x256 tile, BK=32, 4-slot ring, 8 waves (2M x 4N), per-wave 128x64.
__global__ __launch_bounds__(512, 2) void gemm1_swiglu(
    const u16* __restrict__ hid, const u16* __restrict__ gup,
    const int* __restrict__ perm, u16* __restrict__ act) {
  __shared__ u16 As[4][8192];   // 4 x 16 KiB
  __shared__ u16 Bs[4][8192];   // 4 x 16 KiB  (total 128 KiB)
  const int NT = H_ / 32;       // 64 K-tiles

  const int nwg = 6 * 4 * E_;   // 768, %8==0
  const int wid = (blockIdx.x % 8) * (nwg / 8) + blockIdx.x / 8;
  const int e = wid / 24;
  const int mb = (wid / 6) % 4;
  const int nb = wid % 6;

  const int tid = threadIdx.x;
  const int lane = tid & 63, w = tid >> 6;
  const int wr = w >> 2, wc = w & 3;           // 2 x 4 wave grid

  // staging sources: thread covers row (q*128 + tid>>2), 16B chunk (tid&3);
  // chunk pre-swizzled so ds_reads below are conflict-free (T2, rule #21).
  const int srow = tid >> 2, schunk = tid & 3;
  const u16* pA[2]; const u16* pB[2];
#pragma unroll
  for (int q = 0; q < 2; ++q) {
    const int r = q * 128 + srow;
    const int cg = (schunk ^ ((r >> 1) & 3)) * 8;
    const int token = perm[e * G_ + mb * 256 + r] >> 3;
    pA[q] = hid + (size_t)token * H_ + cg;
    pB[q] = gup + ((size_t)e * GU2 + nb * 256 + r) * H_ + cg;
  }

  // ds-read offsets (u16 units), swizzle matches staging pre-swizzle
  int aoff[8], boff[4];
  {
    const int l15 = lane & 15, hk = lane >> 4;
#pragma unroll
    for (int m = 0; m < 8; ++m) {
      const int rA = wr * 128 + m * 16 + l15;
      aoff[m] = rA * 32 + ((hk ^ ((rA >> 1) & 3)) * 8);
    }
#pragma unroll
    for (int n = 0; n < 4; ++n) {
      const int rB = wc * 64 + n * 16 + l15;
      boff[n] = rB * 32 + ((hk ^ ((rB >> 1) & 3)) * 8);
    }
  }

  f32x4 acc[8][4];
#pragma unroll
  for (int m = 0; m < 8; ++m)
#pragma unroll
    for (int n = 0; n < 4; ++n) acc[m][n] = (f32x4){0.f, 0.f, 0.f, 0.f};

  // prologue: stage tiles 0,1 into slots 0,1
  GLOAD16(pA[0], &As[0][tid * 8]);      GLOAD16(pA[1], &As[0][4096 + tid * 8]);
  GLOAD16(pB[0], &Bs[0][tid * 8]);      GLOAD16(pB[1], &Bs[0][4096 + tid * 8]);
  GLOAD16(pA[0] + 32, &As[1][tid * 8]); GLOAD16(pA[1] + 32, &As[1][4096 + tid * 8]);
  GLOAD16(pB[0] + 32, &Bs[1][tid * 8]); GLOAD16(pB[1] + 32, &Bs[1][4096 + tid * 8]);
  VM4(); BAR(); SCHB();

#pragma unroll 4
  for (int t = 0; t < NT; ++t) {
    const int slot = t & 3, ts = (t + 2) & 3;
    const bool st = (t + 2) < NT;
    const u16* Ab = As[slot]; const u16* Bb = Bs[slot];
    bf16x8 av[4], bv[4];
    // ---- phase A: read b[0..3]+a[0..3], stage A(t+2), 16 MFMA
#pragma unroll
    for (int n = 0; n < 4; ++n) bv[n] = *(const bf16x8*)&Bb[boff[n]];
#pragma unroll
    for (int m = 0; m < 4; ++m) av[m] = *(const bf16x8*)&Ab[aoff[m]];
    if (st) {
      GLOAD16(pA[0] + (t + 2) * 32, &As[ts][tid * 8]);
      GLOAD16(pA[1] + (t + 2) * 32, &As[ts][4096 + tid * 8]);
    }
    SCHB(); BAR(); LGKM0(); SCHB();
    __builtin_amdgcn_s_setprio(1);
#pragma unroll
    for (int m = 0; m < 4; ++m)
#pragma unroll
      for (int n = 0; n < 4; ++n)
        acc[m][n] = __builtin_amdgcn_mfma_f32_16x16x32_bf16(av[m], bv[n],
                                                            acc[m][n], 0, 0, 0);
    __builtin_amdgcn_s_setprio(0);
    SCHB(); BAR();
    // ---- phase B: read a[4..7], stage B(t+2), 16 MFMA
#pragma unroll
    for (int m = 0; m < 4; ++m) av[m] = *(const bf16x8*)&Ab[aoff[m + 4]];
    if (st) {
      GLOAD16(pB[0] + (t + 2) * 32, &Bs[ts][tid * 8]);
      GLOAD16(pB[1] + (t + 2) * 32, &Bs[ts][4096 + tid * 8]);
    }
    SCHB(); BAR(); LGKM0(); SCHB();
    __builtin_amdgcn_s_setprio(1);
#pragma unroll
    for (int m = 0; m < 4; ++m)
#pragma unroll
      for (int n = 0; n < 4; ++n)
        acc[m + 4][n] = __builtin_amdgcn_mfma_f32_16x16x32_bf16(av[m], bv[n],
                                                                acc[m + 4][n], 0, 0, 0);
    __builtin_amdgcn_s_setprio(0);
    SCHB();
    if (st) { VM4(); } else { VM0(); }   // tile t+1 fully landed; t+2 in flight
    BAR();
  }

  // epilogue: SwiGLU on paired (gate,up) fragments, store bf16 act
  const int lrow = (lane >> 4) * 4, lcol = lane & 15;
#pragma unroll
  for (int m = 0; m < 8; ++m)
#pragma unroll
    for (int p = 0; p < 2; ++p)
#pragma unroll
      for (int r = 0; r < 4; ++r) {
        const float g = acc[m][2 * p][r];
        const float u = acc[m][2 * p + 1][r];
        const float a_ = g / (1.f + __expf(-g)) * u;     // silu(g)*u
        const int row = mb * 256 + wr * 128 + m * 16 + lrow + r;
        const int dcol = (nb * 8 + wc * 2 + p) * 16 + lcol;
        act[((size_t)e * G_ + row) * D_ + dcol] = f2bf(a_);
      }
}

// --------------------------------------------------------------- GEMM2 -----
// Same structure, K=768; epilogue scatters rows to expanded order.
__global__ __launch_bounds__(512, 2) void gemm2_scatter(
    const u16* __restrict__ act, const u16* __restrict__ dwn,
    const int* __restrict__ perm, u16* __restrict__ expo) {
  __shared__ u16 As[4][8192];
  __shared__ u16 Bs[4][8192];
  const int NT = D_ / 32;       // 24 K-tiles

  const int nwg = 8 * 4 * E_;   // 1024, %8==0
  const int wid = (blockIdx.x % 8) * (nwg / 8) + blockIdx.x / 8;
  const int e = wid / 32;
  const int mb = (wid / 8) % 4;
  const int nb = wid % 8;

  const int tid = threadIdx.x;
  const int lane = tid & 63, w = tid >> 6;
  const int wr = w >> 2, wc = w & 3;

  const int srow = tid >> 2, schunk = tid & 3;
  const u16* pA[2]; const u16* pB[2];
#pragma unroll
  for (int q = 0; q < 2; ++q) {
    const int r = q * 128 + srow;
    const int cg = (schunk ^ ((r >> 1) & 3)) * 8;
    pA[q] = act + ((size_t)e * G_ + mb * 256 + r) * D_ + cg;
    pB[q] = dwn + ((size_t)e * H_ + nb * 256 + r) * D_ + cg;
  }

  int aoff[8], boff[4];
  {
    const int l15 = lane & 15, hk = lane >> 4;
#pragma unroll
    for (int m = 0; m < 8; ++m) {
      const int rA = wr * 128 + m * 16 + l15;
      aoff[m] = rA * 32 + ((hk ^ ((rA >> 1) & 3)) * 8);
    }
#pragma unroll
    for (int n = 0; n < 4; ++n) {
      const int rB = wc * 64 + n * 16 + l15;
      boff[n] = rB * 32 + ((hk ^ ((rB >> 1) & 3)) * 8);
    }
  }

  f32x4 acc[8][4];
#pragma unroll
  for (int m = 0; m < 8; ++m)
#pragma unroll
    for (int n = 0; n < 4; ++n) acc[m][n] = (f32x4){0.f, 0.f, 0.f, 0.f};

  GLOAD16(pA[0], &As[0][tid * 8]);      GLOAD16(pA[1], &As[0][4096 + tid * 8]);
  GLOAD16(pB[0], &Bs[0][tid * 8]);      GLOAD16(pB[1], &Bs[0][4096 + tid * 8]);
  GLOAD16(pA[0] + 32, &As[1][tid * 8]); GLOAD16(pA[1] + 32, &As[1][4096 + tid * 8]);
  GLOAD16(pB[0] + 32, &Bs[1][tid * 8]); GLOAD16(pB[1] + 32, &Bs[1][4096 + tid * 8]);
  VM4(); BAR(); SCHB();

#pragma unroll 4
  for (int t = 0; t < NT; ++t) {
    const int slot = t & 3, ts = (t + 2) & 3;
    const bool st = (t + 2) < NT;
    const u16* Ab = As[slot]; const u16* Bb = Bs[slot];
    bf16x8 av[4], bv[4];
#pragma unroll
    for (int n = 0; n < 4; ++n) bv[n] = *(const bf16x8*)&Bb[boff[n]];
#pragma unroll
    for (int m = 0; m < 4; ++m) av[m] = *(const bf16x8*)&Ab[aoff[m]];
    if (st) {
      GLOAD16(pA[0] + (t + 2) * 32, &As[ts][tid * 8]);
      GLOAD16(pA[1] + (t + 2) * 32, &As[ts][4096 + tid * 8]);
    }
    SCHB(); BAR(); LGKM0(); SCHB();
    __builtin_amdgcn_s_setprio(1);
#pragma unroll
    for (int m = 0; m < 4; ++m)
#pragma unroll
      for (int n = 0; n < 4; ++n)
        acc[m][n] = __builtin_amdgcn_mfma_f32_16x16x32_bf16(av[m], bv[n],
                                                            acc[m][n], 0, 0, 0);
    __builtin_amdgcn_s_setprio(0);
    SCHB(); BAR();
#pragma unroll
    for (int m = 0; m < 4; ++m) av[m] = *(const bf16x8*)&Ab[aoff[m + 4]];
    if (st) {
      GLOAD16(pB[0] + (t + 2) * 32, &Bs[ts][tid * 8]);
      GLOAD16(pB[1] + (t + 2) * 32, &Bs[ts][4096 + tid * 8]);
    }
    SCHB(); BAR(); LGKM0(); SCHB();
    __builtin_amdgcn_s_setprio(1);
#pragma unroll
    for (int m = 0; m < 4; ++m)
#pragma unroll
      for (int n = 0; n < 4; ++n)
        acc[m + 4][n] = __builtin_amdgcn_mfma_f32_16x16x32_bf16(av[m], bv[n],
                                                                acc[m + 4][n], 0, 0, 0);
    __builtin_amdgcn_s_setprio(0);
    SCHB();
    if (st) { VM4(); } else { VM0(); }
    BAR();
  }

  const int lrow = (lane >> 4) * 4, lcol = lane & 15;
#pragma unroll
  for (int m = 0; m < 8; ++m)
#pragma unroll
    for (int r = 0; r < 4; ++r) {
      const int dst = e * G_ + mb * 256 + wr * 128 + m * 16 + lrow + r;
      const int src = perm[dst];                 // expanded index t*K+k
      u16* orow = expo + (size_t)src * H_ + nb * 256 + wc * 64;
#pragma unroll
      for (int n = 0; n < 4; ++n)
        orow[n * 16 + lcol] = f2bf(acc[m][n][r]);
    }
}

// ------------------------------------------------------------- combine -----
__global__ __launch_bounds__(256) void combine(const u16* __restrict__ expo,
                                               const float* __restrict__ probs,
                                               float* __restrict__ out) {
  const int t = blockIdx.x;
  const int h0 = threadIdx.x * 8;
  float r[8] = {0.f, 0.f, 0.f, 0.f, 0.f, 0.f, 0.f, 0.f};
#pragma unroll
  for (int k = 0; k < K_; ++k) {
    const float p = probs[t * K_ + k];
    const u16x8 v = *(const u16x8*)&expo[((size_t)(t * K_ + k)) * H_ + h0];
#pragma unroll
    for (int j = 0; j < 8; ++j) r[j] += p * bf2f(v[j]);
  }
  float4 o0 = {r[0], r[1], r[2], r[3]};
  float4 o1 = {r[4], r[5], r[6], r[7]};
  *(float4*)&out[(size_t)t * H_ + h0]     = o0;
  *(float4*)&out[(size_t)t * H_ + h0 + 4] = o1;
}

// -------------------------------------------------------------- launch -----
extern "C" void kernel_launch(void* const* d_in, const int* in_sizes, int n_in,
                              void* d_out, int out_size, void* d_ws, size_t ws_size,
                              hipStream_t stream) {
  const float* hidden = (const float*)d_in[0];   // (T, H) f32
  const float* rw     = (const float*)d_in[1];   // (T, E) f32
  const int*   ridx   = (const int*)d_in[2];     // (T, K) i32
  const float* gup_f  = (const float*)d_in[3];   // (E, H, 2D) f32
  const float* dwn_f  = (const float*)d_in[4];   // (E, D, H) f32
  float* out = (float*)d_out;                    // (T, H) f32

  char* ws = (char*)d_ws;
  size_t off = 0;
  auto alloc = [&](size_t bytes) -> void* {
    void* p = ws + off;
    off += (bytes + 255) & ~(size_t)255;
    return p;
  };
  u16*   hid_bf = (u16*)alloc((size_t)T_ * H_ * 2);        //  16.8 MB
  u16*   gup_t  = (u16*)alloc((size_t)E_ * GU2 * H_ * 2);  // 201.3 MB (E,1536i,H)
  u16*   dwn_t  = (u16*)alloc((size_t)E_ * H_ * D_ * 2);   // 100.7 MB (E,H,D)
  u16*   act    = (u16*)alloc((size_t)M_ * D_ * 2);        //  50.3 MB
  u16*   expo   = (u16*)alloc((size_t)M_ * H_ * 2);        // 134.2 MB
  int*   perm   = (int*)alloc((size_t)M_ * 4);
  float* probs  = (float*)alloc((size_t)M_ * 4);
  if (off > ws_size) return;   // workspace too small -> clean fail

  cvt_hidden<<<(T_ * H_ / 4) / 256, 256, 0, stream>>>(hidden, hid_bf);
  transpose_cvt<<<dim3(GU2 / 64, H_ / 64, E_), 256, 0, stream>>>(gup_f, gup_t, H_, GU2, 1);
  transpose_cvt<<<dim3(H_ / 64, D_ / 64, E_), 256, 0, stream>>>(dwn_f, dwn_t, D_, H_, 0);
  build_perm<<<E_, 256, 0, stream>>>(ridx, perm);
  gather_probs<<<M_ / 256, 256, 0, stream>>>(ridx, rw, probs);
  gemm1_swiglu<<<6 * 4 * E_, 512, 0, stream>>>(hid_bf, gup_t, perm, act);
  gemm2_scatter<<<8 * 4 * E_, 512, 0, stream>>>(act, dwn_t, perm, expo);
  combine<<<T_, 256, 0, stream>>>(expo, probs, out);
}

// Round 4
// 618.563 us; speedup vs baseline: 1.0882x; 1.0024x over previous
//
#include <hip/hip_runtime.h>
#include <hip/hip_bf16.h>
#include <cstdint>

// Qwen3-VL-MoE text experts: permute -> grouped GEMM (gate_up) -> SwiGLU ->
// grouped GEMM (down) -> unpermute+combine.  bf16 MFMA path.
// R4: depth-3 prefetch (vmcnt(8) steady state) on the 4-slot ring; per-phase
// barrier pairs (T3) + counted vmcnt (T4) + setprio (T5) + swizzle (T2) +
// XCD swizzle (T1) kept from R3.  Transposes rewritten: col-major LDS tile,
// float4 global reads, b128 LDS reads, 16B global stores.

#define E_   32
#define H_   2048
#define D_   768
#define T_   4096
#define K_   8
#define M_   (T_ * K_)   // 32768 expanded rows
#define G_   (M_ / E_)   // 1024 rows per expert (balanced)
#define GU2  (2 * D_)    // 1536

typedef unsigned short u16;
typedef short bf16x8 __attribute__((ext_vector_type(8)));
typedef float f32x4 __attribute__((ext_vector_type(4)));
typedef unsigned short u16x2 __attribute__((ext_vector_type(2)));
typedef unsigned short u16x8 __attribute__((ext_vector_type(8)));

__device__ __forceinline__ u16 f2bf(float f) {          // RNE f32 -> bf16
  unsigned u = __float_as_uint(f);
  u += 0x7FFFu + ((u >> 16) & 1u);
  return (u16)(u >> 16);
}
__device__ __forceinline__ float bf2f(u16 v) {
  return __uint_as_float(((unsigned)v) << 16);
}

#define GLOAD16(g, l) __builtin_amdgcn_global_load_lds(                        \
    (const __attribute__((address_space(1))) void*)(g),                        \
    (__attribute__((address_space(3))) void*)(l), 16, 0, 0)

#define VM8()   asm volatile("s_waitcnt vmcnt(8)" ::: "memory")
#define VM4()   asm volatile("s_waitcnt vmcnt(4)" ::: "memory")
#define VM0()   asm volatile("s_waitcnt vmcnt(0)" ::: "memory")
#define LGKM0() asm volatile("s_waitcnt lgkmcnt(0)" ::: "memory")
#define SCHB()  __builtin_amdgcn_sched_barrier(0)
#define BAR()   __builtin_amdgcn_s_barrier()

// ---------------------------------------------------------------- prep ------
__global__ __launch_bounds__(256) void cvt_hidden(const float* __restrict__ in,
                                                  u16* __restrict__ out) {
  const int i = blockIdx.x * 256 + threadIdx.x;       // float4 groups
  const float4 v = ((const float4*)in)[i];
  u16x2 a; a.x = f2bf(v.x); a.y = f2bf(v.y);
  u16x2 b; b.x = f2bf(v.z); b.y = f2bf(v.w);
  *(u16x2*)&out[(size_t)i * 4]     = a;
  *(u16x2*)&out[(size_t)i * 4 + 2] = b;
}

// in: (B, R, C) f32  ->  out: (B, C, R) bf16, with optional gate/up
// 16-column interleave remap of the output row (mode 1: C==1536,
// gate j -> (j>>4)*32 + (j&15), up j -> (j>>4)*32 + 16 + (j&15)).
// Col-major LDS tile (pitch 72): f32x4 reads, b128 LDS reads, 16B stores.
__global__ __launch_bounds__(256) void transpose_cvt(const float* __restrict__ in,
                                                     u16* __restrict__ out,
                                                     int R, int C, int mode) {
  __shared__ u16 tl[64 * 72];        // tl[c*72 + r]
  const int b = blockIdx.z;
  const int c0 = blockIdx.x * 64, r0 = blockIdx.y * 64;
  const int tid = threadIdx.x;
  const float* ip = in + ((size_t)b * R + r0) * C + c0;
  const int rr4 = tid >> 4;          // 0..15
  const int cc4 = (tid & 15) * 4;    // 0,4,..,60
#pragma unroll
  for (int p = 0; p < 4; ++p) {
    const int r = p * 16 + rr4;
    const float4 v = *(const float4*)&ip[(size_t)r * C + cc4];
    tl[(cc4 + 0) * 72 + r] = f2bf(v.x);
    tl[(cc4 + 1) * 72 + r] = f2bf(v.y);
    tl[(cc4 + 2) * 72 + r] = f2bf(v.z);
    tl[(cc4 + 3) * 72 + r] = f2bf(v.w);
  }
  __syncthreads();
  const int rs = (tid & 7) * 8;      // 8-row strip start
#pragma unroll
  for (int q = 0; q < 2; ++q) {
    const int c = q * 32 + (tid >> 3);
    const int gc = c0 + c;
    int rr;
    if (mode == 1) {
      const int j = (gc < D_) ? gc : (gc - D_);
      rr = (j >> 4) * 32 + ((gc < D_) ? 0 : 16) + (j & 15);
    } else {
      rr = gc;
    }
    const u16x8 v = *(const u16x8*)&tl[c * 72 + rs];
    *(u16x8*)&out[((size_t)b * C + rr) * R + r0 + rs] = v;
  }
}

// ------------------------------------------------------------- routing -----
// Stable counting sort by expert id; balanced groups => base[e] = e*G_.
__global__ __launch_bounds__(256) void build_perm(const int* __restrict__ ridx,
                                                  int* __restrict__ perm_src) {
  const int e = blockIdx.x;
  const int lane = threadIdx.x & 63, wid = threadIdx.x >> 6;
  __shared__ int wcnt[4];
  __shared__ int running;
  if (threadIdx.x == 0) running = 0;
  __syncthreads();
  for (int base = 0; base < M_; base += 256) {
    const int i = base + threadIdx.x;
    const bool match = (ridx[i] == e);
    const unsigned long long mask = __ballot(match);
    if (lane == 0) wcnt[wid] = __popcll(mask);
    __syncthreads();
    int wpre = 0;
    for (int w0 = 0; w0 < wid; ++w0) wpre += wcnt[w0];
    const int rank = __popcll(mask & ((1ull << lane) - 1ull));
    if (match) perm_src[e * G_ + running + wpre + rank] = i;
    __syncthreads();
    if (threadIdx.x == 0) running += wcnt[0] + wcnt[1] + wcnt[2] + wcnt[3];
    __syncthreads();
  }
}

__global__ __launch_bounds__(256) void gather_probs(const int* __restrict__ ridx,
                                                    const float* __restrict__ rw,
                                                    float* __restrict__ probs) {
  const int i = blockIdx.x * 256 + threadIdx.x;   // i < M_
  const int t = i >> 3;
  probs[i] = rw[t * E_ + ridx[i]];
}

// --------------------------------------------------------------- GEMM1 -----
// 256x256 tile, BK=32, 4-slot ring, depth-3 prefetch, 8 waves (2M x 4N).
__global__ __launch_bounds__(512, 2) void gemm1_swiglu(
    const u16* __restrict__ hid, const u16* __restrict__ gup,
    const int* __restrict__ perm, u16* __restrict__ act) {
  __shared__ u16 As[4][8192];   // 4 x 16 KiB
  __shared__ u16 Bs[4][8192];   // 4 x 16 KiB  (total 128 KiB)
  const int NT = H_ / 32;       // 64 K-tiles

  const int nwg = 6 * 4 * E_;   // 768, %8==0
  const int wid = (blockIdx.x % 8) * (nwg / 8) + blockIdx.x / 8;
  const int e = wid / 24;
  const int mb = (wid / 6) % 4;
  const int nb = wid % 6;

  const int tid = threadIdx.x;
  const int lane = tid & 63, w = tid >> 6;
  const int wr = w >> 2, wc = w & 3;           // 2 x 4 wave grid

  // staging sources: thread covers row (q*128 + tid>>2), 16B chunk (tid&3);
  // chunk pre-swizzled so ds_reads below are conflict-free (T2, rule #21).
  const int srow = tid >> 2, schunk = tid & 3;
  const u16* pA[2]; const u16* pB[2];
#pragma unroll
  for (int q = 0; q < 2; ++q) {
    const int r = q * 128 + srow;
    const int cg = (schunk ^ ((r >> 1) & 3)) * 8;
    const int token = perm[e * G_ + mb * 256 + r] >> 3;
    pA[q] = hid + (size_t)token * H_ + cg;
    pB[q] = gup + ((size_t)e * GU2 + nb * 256 + r) * H_ + cg;
  }

  // ds-read offsets (u16 units), swizzle matches staging pre-swizzle
  int aoff[8], boff[4];
  {
    const int l15 = lane & 15, hk = lane >> 4;
#pragma unroll
    for (int m = 0; m < 8; ++m) {
      const int rA = wr * 128 + m * 16 + l15;
      aoff[m] = rA * 32 + ((hk ^ ((rA >> 1) & 3)) * 8);
    }
#pragma unroll
    for (int n = 0; n < 4; ++n) {
      const int rB = wc * 64 + n * 16 + l15;
      boff[n] = rB * 32 + ((hk ^ ((rB >> 1) & 3)) * 8);
    }
  }

  f32x4 acc[8][4];
#pragma unroll
  for (int m = 0; m < 8; ++m)
#pragma unroll
    for (int n = 0; n < 4; ++n) acc[m][n] = (f32x4){0.f, 0.f, 0.f, 0.f};

  // prologue: stage tiles 0,1,2 into slots 0,1,2 (issue order = tile order)
  GLOAD16(pA[0], &As[0][tid * 8]);      GLOAD16(pA[1], &As[0][4096 + tid * 8]);
  GLOAD16(pB[0], &Bs[0][tid * 8]);      GLOAD16(pB[1], &Bs[0][4096 + tid * 8]);
  GLOAD16(pA[0] + 32, &As[1][tid * 8]); GLOAD16(pA[1] + 32, &As[1][4096 + tid * 8]);
  GLOAD16(pB[0] + 32, &Bs[1][tid * 8]); GLOAD16(pB[1] + 32, &Bs[1][4096 + tid * 8]);
  GLOAD16(pA[0] + 64, &As[2][tid * 8]); GLOAD16(pA[1] + 64, &As[2][4096 + tid * 8]);
  GLOAD16(pB[0] + 64, &Bs[2][tid * 8]); GLOAD16(pB[1] + 64, &Bs[2][4096 + tid * 8]);
  VM8(); BAR(); SCHB();                 // tile 0 landed; tiles 1,2 in flight

#pragma unroll 4
  for (int t = 0; t < NT; ++t) {
    const int slot = t & 3, ts = (t + 3) & 3;
    const bool st = (t + 3) < NT;
    const u16* Ab = As[slot]; const u16* Bb = Bs[slot];
    bf16x8 av[4], bv[4];
    // ---- phase A: read b[0..3]+a[0..3], stage A(t+3), 16 MFMA
#pragma unroll
    for (int n = 0; n < 4; ++n) bv[n] = *(const bf16x8*)&Bb[boff[n]];
#pragma unroll
    for (int m = 0; m < 4; ++m) av[m] = *(const bf16x8*)&Ab[aoff[m]];
    if (st) {
      GLOAD16(pA[0] + (t + 3) * 32, &As[ts][tid * 8]);
      GLOAD16(pA[1] + (t + 3) * 32, &As[ts][4096 + tid * 8]);
    }
    SCHB(); BAR(); LGKM0(); SCHB();
    __builtin_amdgcn_s_setprio(1);
#pragma unroll
    for (int m = 0; m < 4; ++m)
#pragma unroll
      for (int n = 0; n < 4; ++n)
        acc[m][n] = __builtin_amdgcn_mfma_f32_16x16x32_bf16(av[m], bv[n],
                                                            acc[m][n], 0, 0, 0);
    __builtin_amdgcn_s_setprio(0);
    SCHB(); BAR();
    // ---- phase B: read a[4..7], stage B(t+3), 16 MFMA
#pragma unroll
    for (int m = 0; m < 4; ++m) av[m] = *(const bf16x8*)&Ab[aoff[m + 4]];
    if (st) {
      GLOAD16(pB[0] + (t + 3) * 32, &Bs[ts][tid * 8]);
      GLOAD16(pB[1] + (t + 3) * 32, &Bs[ts][4096 + tid * 8]);
    }
    SCHB(); BAR(); LGKM0(); SCHB();
    __builtin_amdgcn_s_setprio(1);
#pragma unroll
    for (int m = 0; m < 4; ++m)
#pragma unroll
      for (int n = 0; n < 4; ++n)
        acc[m + 4][n] = __builtin_amdgcn_mfma_f32_16x16x32_bf16(av[m], bv[n],
                                                                acc[m + 4][n], 0, 0, 0);
    __builtin_amdgcn_s_setprio(0);
    SCHB();
    // ---- boundary: tile t+1 must be landed; up to 8 younger loads in flight
    if (t + 3 < NT)      { VM8(); }
    else if (t + 2 < NT) { VM4(); }
    else                 { VM0(); }
    BAR();
  }

  // epilogue: SwiGLU on paired (gate,up) fragments, store bf16 act
  const int lrow = (lane >> 4) * 4, lcol = lane & 15;
#pragma unroll
  for (int m = 0; m < 8; ++m)
#pragma unroll
    for (int p = 0; p < 2; ++p)
#pragma unroll
      for (int r = 0; r < 4; ++r) {
        const float g = acc[m][2 * p][r];
        const float u = acc[m][2 * p + 1][r];
        const float a_ = g / (1.f + __expf(-g)) * u;     // silu(g)*u
        const int row = mb * 256 + wr * 128 + m * 16 + lrow + r;
        const int dcol = (nb * 8 + wc * 2 + p) * 16 + lcol;
        act[((size_t)e * G_ + row) * D_ + dcol] = f2bf(a_);
      }
}

// --------------------------------------------------------------- GEMM2 -----
// Same structure, K=768; epilogue scatters rows to expanded order.
__global__ __launch_bounds__(512, 2) void gemm2_scatter(
    const u16* __restrict__ act, const u16* __restrict__ dwn,
    const int* __restrict__ perm, u16* __restrict__ expo) {
  __shared__ u16 As[4][8192];
  __shared__ u16 Bs[4][8192];
  const int NT = D_ / 32;       // 24 K-tiles

  const int nwg = 8 * 4 * E_;   // 1024, %8==0
  const int wid = (blockIdx.x % 8) * (nwg / 8) + blockIdx.x / 8;
  const int e = wid / 32;
  const int mb = (wid / 8) % 4;
  const int nb = wid % 8;

  const int tid = threadIdx.x;
  const int lane = tid & 63, w = tid >> 6;
  const int wr = w >> 2, wc = w & 3;

  const int srow = tid >> 2, schunk = tid & 3;
  const u16* pA[2]; const u16* pB[2];
#pragma unroll
  for (int q = 0; q < 2; ++q) {
    const int r = q * 128 + srow;
    const int cg = (schunk ^ ((r >> 1) & 3)) * 8;
    pA[q] = act + ((size_t)e * G_ + mb * 256 + r) * D_ + cg;
    pB[q] = dwn + ((size_t)e * H_ + nb * 256 + r) * D_ + cg;
  }

  int aoff[8], boff[4];
  {
    const int l15 = lane & 15, hk = lane >> 4;
#pragma unroll
    for (int m = 0; m < 8; ++m) {
      const int rA = wr * 128 + m * 16 + l15;
      aoff[m] = rA * 32 + ((hk ^ ((rA >> 1) & 3)) * 8);
    }
#pragma unroll
    for (int n = 0; n < 4; ++n) {
      const int rB = wc * 64 + n * 16 + l15;
      boff[n] = rB * 32 + ((hk ^ ((rB >> 1) & 3)) * 8);
    }
  }

  f32x4 acc[8][4];
#pragma unroll
  for (int m = 0; m < 8; ++m)
#pragma unroll
    for (int n = 0; n < 4; ++n) acc[m][n] = (f32x4){0.f, 0.f, 0.f, 0.f};

  GLOAD16(pA[0], &As[0][tid * 8]);      GLOAD16(pA[1], &As[0][4096 + tid * 8]);
  GLOAD16(pB[0], &Bs[0][tid * 8]);      GLOAD16(pB[1], &Bs[0][4096 + tid * 8]);
  GLOAD16(pA[0] + 32, &As[1][tid * 8]); GLOAD16(pA[1] + 32, &As[1][4096 + tid * 8]);
  GLOAD16(pB[0] + 32, &Bs[1][tid * 8]); GLOAD16(pB[1] + 32, &Bs[1][4096 + tid * 8]);
  GLOAD16(pA[0] + 64, &As[2][tid * 8]); GLOAD16(pA[1] + 64, &As[2][4096 + tid * 8]);
  GLOAD16(pB[0] + 64, &Bs[2][tid * 8]); GLOAD16(pB[1] + 64, &Bs[2][4096 + tid * 8]);
  VM8(); BAR(); SCHB();

#pragma unroll 4
  for (int t = 0; t < NT; ++t) {
    const int slot = t & 3, ts = (t + 3) & 3;
    const bool st = (t + 3) < NT;
    const u16* Ab = As[slot]; const u16* Bb = Bs[slot];
    bf16x8 av[4], bv[4];
#pragma unroll
    for (int n = 0; n < 4; ++n) bv[n] = *(const bf16x8*)&Bb[boff[n]];
#pragma unroll
    for (int m = 0; m < 4; ++m) av[m] = *(const bf16x8*)&Ab[aoff[m]];
    if (st) {
      GLOAD16(pA[0] + (t + 3) * 32, &As[ts][tid * 8]);
      GLOAD16(pA[1] + (t + 3) * 32, &As[ts][4096 + tid * 8]);
    }
    SCHB(); BAR(); LGKM0(); SCHB();
    __builtin_amdgcn_s_setprio(1);
#pragma unroll
    for (int m = 0; m < 4; ++m)
#pragma unroll
      for (int n = 0; n < 4; ++n)
        acc[m][n] = __builtin_amdgcn_mfma_f32_16x16x32_bf16(av[m], bv[n],
                                                            acc[m][n], 0, 0, 0);
    __builtin_amdgcn_s_setprio(0);
    SCHB(); BAR();
#pragma unroll
    for (int m = 0; m < 4; ++m) av[m] = *(const bf16x8*)&Ab[aoff[m + 4]];
    if (st) {
      GLOAD16(pB[0] + (t + 3) * 32, &Bs[ts][tid * 8]);
      GLOAD16(pB[1] + (t + 3) * 32, &Bs[ts][4096 + tid * 8]);
    }
    SCHB(); BAR(); LGKM0(); SCHB();
    __builtin_amdgcn_s_setprio(1);
#pragma unroll
    for (int m = 0; m < 4; ++m)
#pragma unroll
      for (int n = 0; n < 4; ++n)
        acc[m + 4][n] = __builtin_amdgcn_mfma_f32_16x16x32_bf16(av[m], bv[n],
                                                                acc[m + 4][n], 0, 0, 0);
    __builtin_amdgcn_s_setprio(0);
    SCHB();
    if (t + 3 < NT)      { VM8(); }
    else if (t + 2 < NT) { VM4(); }
    else                 { VM0(); }
    BAR();
  }

  const int lrow = (lane >> 4) * 4, lcol = lane & 15;
#pragma unroll
  for (int m = 0; m < 8; ++m)
#pragma unroll
    for (int r = 0; r < 4; ++r) {
      const int dst = e * G_ + mb * 256 + wr * 128 + m * 16 + lrow + r;
      const int src = perm[dst];                 // expanded index t*K+k
      u16* orow = expo + (size_t)src * H_ + nb * 256 + wc * 64;
#pragma unroll
      for (int n = 0; n < 4; ++n)
        orow[n * 16 + lcol] = f2bf(acc[m][n][r]);
    }
}

// ------------------------------------------------------------- combine -----
__global__ __launch_bounds__(256) void combine(const u16* __restrict__ expo,
                                               const float* __restrict__ probs,
                                               float* __restrict__ out) {
  const int t = blockIdx.x;
  const int h0 = threadIdx.x * 8;
  float r[8] = {0.f, 0.f, 0.f, 0.f, 0.f, 0.f, 0.f, 0.f};
#pragma unroll
  for (int k = 0; k < K_; ++k) {
    const float p = probs[t * K_ + k];
    const u16x8 v = *(const u16x8*)&expo[((size_t)(t * K_ + k)) * H_ + h0];
#pragma unroll
    for (int j = 0; j < 8; ++j) r[j] += p * bf2f(v[j]);
  }
  float4 o0 = {r[0], r[1], r[2], r[3]};
  float4 o1 = {r[4], r[5], r[6], r[7]};
  *(float4*)&out[(size_t)t * H_ + h0]     = o0;
  *(float4*)&out[(size_t)t * H_ + h0 + 4] = o1;
}

// -------------------------------------------------------------- launch -----
extern "C" void kernel_launch(void* const* d_in, const int* in_sizes, int n_in,
                              void* d_out, int out_size, void* d_ws, size_t ws_size,
                              hipStream_t stream) {
  const float* hidden = (const float*)d_in[0];   // (T, H) f32
  const float* rw     = (const float*)d_in[1];   // (T, E) f32
  const int*   ridx   = (const int*)d_in[2];     // (T, K) i32
  const float* gup_f  = (const float*)d_in[3];   // (E, H, 2D) f32
  const float* dwn_f  = (const float*)d_in[4];   // (E, D, H) f32
  float* out = (float*)d_out;                    // (T, H) f32

  char* ws = (char*)d_ws;
  size_t off = 0;
  auto alloc = [&](size_t bytes) -> void* {
    void* p = ws + off;
    off += (bytes + 255) & ~(size_t)255;
    return p;
  };
  u16*   hid_bf = (u16*)alloc((size_t)T_ * H_ * 2);        //  16.8 MB
  u16*   gup_t  = (u16*)alloc((size_t)E_ * GU2 * H_ * 2);  // 201.3 MB (E,1536i,H)
  u16*   dwn_t  = (u16*)alloc((size_t)E_ * H_ * D_ * 2);   // 100.7 MB (E,H,D)
  u16*   act    = (u16*)alloc((size_t)M_ * D_ * 2);        //  50.3 MB
  u16*   expo   = (u16*)alloc((size_t)M_ * H_ * 2);        // 134.2 MB
  int*   perm   = (int*)alloc((size_t)M_ * 4);
  float* probs  = (float*)alloc((size_t)M_ * 4);
  if (off > ws_size) return;   // workspace too small -> clean fail

  cvt_hidden<<<(T_ * H_ / 4) / 256, 256, 0, stream>>>(hidden, hid_bf);
  transpose_cvt<<<dim3(GU2 / 64, H_ / 64, E_), 256, 0, stream>>>(gup_f, gup_t, H_, GU2, 1);
  transpose_cvt<<<dim3(H_ / 64, D_ / 64, E_), 256, 0, stream>>>(dwn_f, dwn_t, D_, H_, 0);
  build_perm<<<E_, 256, 0, stream>>>(ridx, perm);
  gather_probs<<<M_ / 256, 256, 0, stream>>>(ridx, rw, probs);
  gemm1_swiglu<<<6 * 4 * E_, 512, 0, stream>>>(hid_bf, gup_t, perm, act);
  gemm2_scatter<<<8 * 4 * E_, 512, 0, stream>>>(act, dwn_t, perm, expo);
  combine<<<T_, 256, 0, stream>>>(expo, probs, out);
}

// Round 5
// 564.214 us; speedup vs baseline: 1.1931x; 1.0963x over previous
//
#include <hip/hip_runtime.h>
#include <hip/hip_bf16.h>
#include <cstdint>

// Qwen3-VL-MoE text experts: permute -> grouped GEMM (gate_up) -> SwiGLU ->
// grouped GEMM (down) -> unpermute+combine.  bf16 MFMA path.
// R5: GEMMs moved to mfma_f32_32x32x16_bf16 (half the MFMA instrs, higher
// pipe ceiling); depth-3 4-slot ring + T1..T5 schedule kept from R4.
// build_perm -> two-level atomic ranking; gather_probs fused into combine.

#define E_   32
#define H_   2048
#define D_   768
#define T_   4096
#define K_   8
#define M_   (T_ * K_)   // 32768 expanded rows
#define G_   (M_ / E_)   // 1024 rows per expert (balanced)
#define GU2  (2 * D_)    // 1536

typedef unsigned short u16;
typedef short bf16x8 __attribute__((ext_vector_type(8)));
typedef float f32x16 __attribute__((ext_vector_type(16)));
typedef unsigned short u16x2 __attribute__((ext_vector_type(2)));
typedef unsigned short u16x8 __attribute__((ext_vector_type(8)));

__device__ __forceinline__ u16 f2bf(float f) {          // RNE f32 -> bf16
  unsigned u = __float_as_uint(f);
  u += 0x7FFFu + ((u >> 16) & 1u);
  return (u16)(u >> 16);
}
__device__ __forceinline__ float bf2f(u16 v) {
  return __uint_as_float(((unsigned)v) << 16);
}

#define GLOAD16(g, l) __builtin_amdgcn_global_load_lds(                        \
    (const __attribute__((address_space(1))) void*)(g),                        \
    (__attribute__((address_space(3))) void*)(l), 16, 0, 0)

#define VM8()   asm volatile("s_waitcnt vmcnt(8)" ::: "memory")
#define VM4()   asm volatile("s_waitcnt vmcnt(4)" ::: "memory")
#define VM0()   asm volatile("s_waitcnt vmcnt(0)" ::: "memory")
#define LGKM0() asm volatile("s_waitcnt lgkmcnt(0)" ::: "memory")
#define SCHB()  __builtin_amdgcn_sched_barrier(0)
#define BAR()   __builtin_amdgcn_s_barrier()

// ---------------------------------------------------------------- prep ------
__global__ __launch_bounds__(256) void cvt_hidden(const float* __restrict__ in,
                                                  u16* __restrict__ out) {
  const int i = blockIdx.x * 256 + threadIdx.x;       // float4 groups
  const float4 v = ((const float4*)in)[i];
  u16x2 a; a.x = f2bf(v.x); a.y = f2bf(v.y);
  u16x2 b; b.x = f2bf(v.z); b.y = f2bf(v.w);
  *(u16x2*)&out[(size_t)i * 4]     = a;
  *(u16x2*)&out[(size_t)i * 4 + 2] = b;
}

// in: (B, R, C) f32  ->  out: (B, C, R) bf16, with optional gate/up
// 32-column interleave remap (mode 1: C==1536,
// gate j -> (j>>5)*64 + (j&31), up j -> (j>>5)*64 + 32 + (j&31)).
// Col-major LDS tile (pitch 72): f32x4 reads, b128 LDS reads, 16B stores.
__global__ __launch_bounds__(256) void transpose_cvt(const float* __restrict__ in,
                                                     u16* __restrict__ out,
                                                     int R, int C, int mode) {
  __shared__ u16 tl[64 * 72];        // tl[c*72 + r]
  const int b = blockIdx.z;
  const int c0 = blockIdx.x * 64, r0 = blockIdx.y * 64;
  const int tid = threadIdx.x;
  const float* ip = in + ((size_t)b * R + r0) * C + c0;
  const int rr4 = tid >> 4;          // 0..15
  const int cc4 = (tid & 15) * 4;    // 0,4,..,60
#pragma unroll
  for (int p = 0; p < 4; ++p) {
    const int r = p * 16 + rr4;
    const float4 v = *(const float4*)&ip[(size_t)r * C + cc4];
    tl[(cc4 + 0) * 72 + r] = f2bf(v.x);
    tl[(cc4 + 1) * 72 + r] = f2bf(v.y);
    tl[(cc4 + 2) * 72 + r] = f2bf(v.z);
    tl[(cc4 + 3) * 72 + r] = f2bf(v.w);
  }
  __syncthreads();
  const int rs = (tid & 7) * 8;      // 8-row strip start
#pragma unroll
  for (int q = 0; q < 2; ++q) {
    const int c = q * 32 + (tid >> 3);
    const int gc = c0 + c;
    int rr;
    if (mode == 1) {
      const int j = (gc < D_) ? gc : (gc - D_);
      rr = (j >> 5) * 64 + ((gc < D_) ? 0 : 32) + (j & 31);
    } else {
      rr = gc;
    }
    const u16x8 v = *(const u16x8*)&tl[c * 72 + rs];
    *(u16x8*)&out[((size_t)b * C + rr) * R + r0 + rs] = v;
  }
}

// ------------------------------------------------------------- routing -----
// Two-level atomic ranking: LDS histogram + one global atomicAdd per expert
// per block.  Order within an expert group is arbitrary; output values are
// independent of it (each row's dot products don't depend on its position).
__global__ __launch_bounds__(256) void build_perm_fast(const int* __restrict__ ridx,
                                                       int* __restrict__ perm,
                                                       int* __restrict__ gcnt) {
  __shared__ int lc[E_];
  __shared__ int lb[E_];
  const int tid = threadIdx.x;
  if (tid < E_) lc[tid] = 0;
  __syncthreads();
  const int i = blockIdx.x * 256 + tid;
  const int e = ridx[i];
  const int p = atomicAdd(&lc[e], 1);
  __syncthreads();
  if (tid < E_) lb[tid] = atomicAdd(&gcnt[tid], lc[tid]);
  __syncthreads();
  perm[e * G_ + lb[e] + p] = i;
}

// --------------------------------------------------------------- GEMM1 -----
// 256x256 tile, BK=32, 4-slot ring, depth-3 prefetch, 8 waves (2M x 4N),
// per-wave 128x64 via 4x2 mfma_32x32x16 tiles.
__global__ __launch_bounds__(512, 2) void gemm1_swiglu(
    const u16* __restrict__ hid, const u16* __restrict__ gup,
    const int* __restrict__ perm, u16* __restrict__ act) {
  __shared__ u16 As[4][8192];   // 4 x 16 KiB
  __shared__ u16 Bs[4][8192];   // 4 x 16 KiB  (total 128 KiB)
  const int NT = H_ / 32;       // 64 K-tiles

  const int nwg = 6 * 4 * E_;   // 768, %8==0
  const int wid = (blockIdx.x % 8) * (nwg / 8) + blockIdx.x / 8;
  const int e = wid / 24;
  const int mb = (wid / 6) % 4;
  const int nb = wid % 6;

  const int tid = threadIdx.x;
  const int lane = tid & 63, w = tid >> 6;
  const int wr = w >> 2, wc = w & 3;           // 2 x 4 wave grid

  // staging sources: thread covers row (q*128 + tid>>2), 16B chunk (tid&3);
  // chunk pre-swizzled so ds_reads below are conflict-free (T2, rule #21).
  const int srow = tid >> 2, schunk = tid & 3;
  const u16* pA[2]; const u16* pB[2];
#pragma unroll
  for (int q = 0; q < 2; ++q) {
    const int r = q * 128 + srow;
    const int cg = (schunk ^ ((r >> 1) & 3)) * 8;
    const int token = perm[e * G_ + mb * 256 + r] >> 3;
    pA[q] = hid + (size_t)token * H_ + cg;
    pB[q] = gup + ((size_t)e * GU2 + nb * 256 + r) * H_ + cg;
  }

  // ds-read offsets (u16 units) for 32x32x16 fragments:
  // row = base + blk*32 + (lane&31); k-chunk = ks*2 + (lane>>5), XOR-swizzled.
  const int l31 = lane & 31, hi = lane >> 5;
  int aoff[4][2], boff[2][2];
#pragma unroll
  for (int m = 0; m < 4; ++m) {
    const int rA = wr * 128 + m * 32 + l31;
#pragma unroll
    for (int ks = 0; ks < 2; ++ks)
      aoff[m][ks] = rA * 32 + (((ks * 2 + hi) ^ ((rA >> 1) & 3)) * 8);
  }
#pragma unroll
  for (int n = 0; n < 2; ++n) {
    const int rB = wc * 64 + n * 32 + l31;
#pragma unroll
    for (int ks = 0; ks < 2; ++ks)
      boff[n][ks] = rB * 32 + (((ks * 2 + hi) ^ ((rB >> 1) & 3)) * 8);
  }

  f32x16 acc[4][2];
#pragma unroll
  for (int m = 0; m < 4; ++m)
#pragma unroll
    for (int n = 0; n < 2; ++n)
#pragma unroll
      for (int r = 0; r < 16; ++r) acc[m][n][r] = 0.f;

  // prologue: stage tiles 0,1,2 into slots 0,1,2 (issue order = tile order)
  GLOAD16(pA[0], &As[0][tid * 8]);      GLOAD16(pA[1], &As[0][4096 + tid * 8]);
  GLOAD16(pB[0], &Bs[0][tid * 8]);      GLOAD16(pB[1], &Bs[0][4096 + tid * 8]);
  GLOAD16(pA[0] + 32, &As[1][tid * 8]); GLOAD16(pA[1] + 32, &As[1][4096 + tid * 8]);
  GLOAD16(pB[0] + 32, &Bs[1][tid * 8]); GLOAD16(pB[1] + 32, &Bs[1][4096 + tid * 8]);
  GLOAD16(pA[0] + 64, &As[2][tid * 8]); GLOAD16(pA[1] + 64, &As[2][4096 + tid * 8]);
  GLOAD16(pB[0] + 64, &Bs[2][tid * 8]); GLOAD16(pB[1] + 64, &Bs[2][4096 + tid * 8]);
  VM8(); BAR(); SCHB();                 // tile 0 landed; tiles 1,2 in flight

#pragma unroll 4
  for (int t = 0; t < NT; ++t) {
    const int slot = t & 3, ts = (t + 3) & 3;
    const bool st = (t + 3) < NT;
    const u16* Ab = As[slot]; const u16* Bb = Bs[slot];
    bf16x8 av[4], bv[2];
    // ---- phase A (k-step 0): read frags, stage A(t+3), 8 MFMA
#pragma unroll
    for (int n = 0; n < 2; ++n) bv[n] = *(const bf16x8*)&Bb[boff[n][0]];
#pragma unroll
    for (int m = 0; m < 4; ++m) av[m] = *(const bf16x8*)&Ab[aoff[m][0]];
    if (st) {
      GLOAD16(pA[0] + (t + 3) * 32, &As[ts][tid * 8]);
      GLOAD16(pA[1] + (t + 3) * 32, &As[ts][4096 + tid * 8]);
    }
    SCHB(); BAR(); LGKM0(); SCHB();
    __builtin_amdgcn_s_setprio(1);
#pragma unroll
    for (int m = 0; m < 4; ++m)
#pragma unroll
      for (int n = 0; n < 2; ++n)
        acc[m][n] = __builtin_amdgcn_mfma_f32_32x32x16_bf16(av[m], bv[n],
                                                            acc[m][n], 0, 0, 0);
    __builtin_amdgcn_s_setprio(0);
    SCHB(); BAR();
    // ---- phase B (k-step 1): read frags, stage B(t+3), 8 MFMA
#pragma unroll
    for (int n = 0; n < 2; ++n) bv[n] = *(const bf16x8*)&Bb[boff[n][1]];
#pragma unroll
    for (int m = 0; m < 4; ++m) av[m] = *(const bf16x8*)&Ab[aoff[m][1]];
    if (st) {
      GLOAD16(pB[0] + (t + 3) * 32, &Bs[ts][tid * 8]);
      GLOAD16(pB[1] + (t + 3) * 32, &Bs[ts][4096 + tid * 8]);
    }
    SCHB(); BAR(); LGKM0(); SCHB();
    __builtin_amdgcn_s_setprio(1);
#pragma unroll
    for (int m = 0; m < 4; ++m)
#pragma unroll
      for (int n = 0; n < 2; ++n)
        acc[m][n] = __builtin_amdgcn_mfma_f32_32x32x16_bf16(av[m], bv[n],
                                                            acc[m][n], 0, 0, 0);
    __builtin_amdgcn_s_setprio(0);
    SCHB();
    // ---- boundary: tile t+1 must be landed; up to 8 younger loads in flight
    if (t + 3 < NT)      { VM8(); }
    else if (t + 2 < NT) { VM4(); }
    else                 { VM0(); }
    BAR();
  }

  // epilogue: SwiGLU on paired (gate=n0, up=n1) fragments, store bf16 act
  // C/D 32x32: col = lane&31, row = (reg&3) + 8*(reg>>2) + 4*(lane>>5)
#pragma unroll
  for (int m = 0; m < 4; ++m)
#pragma unroll
    for (int r = 0; r < 16; ++r) {
      const float g = acc[m][0][r];
      const float u = acc[m][1][r];
      const float a_ = g / (1.f + __expf(-g)) * u;       // silu(g)*u
      const int row = mb * 256 + wr * 128 + m * 32 + (r & 3) + 8 * (r >> 2) + 4 * hi;
      const int dcol = (nb * 4 + wc) * 32 + l31;
      act[((size_t)e * G_ + row) * D_ + dcol] = f2bf(a_);
    }
}

// --------------------------------------------------------------- GEMM2 -----
// Same structure, K=768; epilogue scatters rows to expanded order.
__global__ __launch_bounds__(512, 2) void gemm2_scatter(
    const u16* __restrict__ act, const u16* __restrict__ dwn,
    const int* __restrict__ perm, u16* __restrict__ expo) {
  __shared__ u16 As[4][8192];
  __shared__ u16 Bs[4][8192];
  const int NT = D_ / 32;       // 24 K-tiles

  const int nwg = 8 * 4 * E_;   // 1024, %8==0
  const int wid = (blockIdx.x % 8) * (nwg / 8) + blockIdx.x / 8;
  const int e = wid / 32;
  const int mb = (wid / 8) % 4;
  const int nb = wid % 8;

  const int tid = threadIdx.x;
  const int lane = tid & 63, w = tid >> 6;
  const int wr = w >> 2, wc = w & 3;

  const int srow = tid >> 2, schunk = tid & 3;
  const u16* pA[2]; const u16* pB[2];
#pragma unroll
  for (int q = 0; q < 2; ++q) {
    const int r = q * 128 + srow;
    const int cg = (schunk ^ ((r >> 1) & 3)) * 8;
    pA[q] = act + ((size_t)e * G_ + mb * 256 + r) * D_ + cg;
    pB[q] = dwn + ((size_t)e * H_ + nb * 256 + r) * D_ + cg;
  }

  const int l31 = lane & 31, hi = lane >> 5;
  int aoff[4][2], boff[2][2];
#pragma unroll
  for (int m = 0; m < 4; ++m) {
    const int rA = wr * 128 + m * 32 + l31;
#pragma unroll
    for (int ks = 0; ks < 2; ++ks)
      aoff[m][ks] = rA * 32 + (((ks * 2 + hi) ^ ((rA >> 1) & 3)) * 8);
  }
#pragma unroll
  for (int n = 0; n < 2; ++n) {
    const int rB = wc * 64 + n * 32 + l31;
#pragma unroll
    for (int ks = 0; ks < 2; ++ks)
      boff[n][ks] = rB * 32 + (((ks * 2 + hi) ^ ((rB >> 1) & 3)) * 8);
  }

  f32x16 acc[4][2];
#pragma unroll
  for (int m = 0; m < 4; ++m)
#pragma unroll
    for (int n = 0; n < 2; ++n)
#pragma unroll
      for (int r = 0; r < 16; ++r) acc[m][n][r] = 0.f;

  GLOAD16(pA[0], &As[0][tid * 8]);      GLOAD16(pA[1], &As[0][4096 + tid * 8]);
  GLOAD16(pB[0], &Bs[0][tid * 8]);      GLOAD16(pB[1], &Bs[0][4096 + tid * 8]);
  GLOAD16(pA[0] + 32, &As[1][tid * 8]); GLOAD16(pA[1] + 32, &As[1][4096 + tid * 8]);
  GLOAD16(pB[0] + 32, &Bs[1][tid * 8]); GLOAD16(pB[1] + 32, &Bs[1][4096 + tid * 8]);
  GLOAD16(pA[0] + 64, &As[2][tid * 8]); GLOAD16(pA[1] + 64, &As[2][4096 + tid * 8]);
  GLOAD16(pB[0] + 64, &Bs[2][tid * 8]); GLOAD16(pB[1] + 64, &Bs[2][4096 + tid * 8]);
  VM8(); BAR(); SCHB();

#pragma unroll 4
  for (int t = 0; t < NT; ++t) {
    const int slot = t & 3, ts = (t + 3) & 3;
    const bool st = (t + 3) < NT;
    const u16* Ab = As[slot]; const u16* Bb = Bs[slot];
    bf16x8 av[4], bv[2];
#pragma unroll
    for (int n = 0; n < 2; ++n) bv[n] = *(const bf16x8*)&Bb[boff[n][0]];
#pragma unroll
    for (int m = 0; m < 4; ++m) av[m] = *(const bf16x8*)&Ab[aoff[m][0]];
    if (st) {
      GLOAD16(pA[0] + (t + 3) * 32, &As[ts][tid * 8]);
      GLOAD16(pA[1] + (t + 3) * 32, &As[ts][4096 + tid * 8]);
    }
    SCHB(); BAR(); LGKM0(); SCHB();
    __builtin_amdgcn_s_setprio(1);
#pragma unroll
    for (int m = 0; m < 4; ++m)
#pragma unroll
      for (int n = 0; n < 2; ++n)
        acc[m][n] = __builtin_amdgcn_mfma_f32_32x32x16_bf16(av[m], bv[n],
                                                            acc[m][n], 0, 0, 0);
    __builtin_amdgcn_s_setprio(0);
    SCHB(); BAR();
#pragma unroll
    for (int n = 0; n < 2; ++n) bv[n] = *(const bf16x8*)&Bb[boff[n][1]];
#pragma unroll
    for (int m = 0; m < 4; ++m) av[m] = *(const bf16x8*)&Ab[aoff[m][1]];
    if (st) {
      GLOAD16(pB[0] + (t + 3) * 32, &Bs[ts][tid * 8]);
      GLOAD16(pB[1] + (t + 3) * 32, &Bs[ts][4096 + tid * 8]);
    }
    SCHB(); BAR(); LGKM0(); SCHB();
    __builtin_amdgcn_s_setprio(1);
#pragma unroll
    for (int m = 0; m < 4; ++m)
#pragma unroll
      for (int n = 0; n < 2; ++n)
        acc[m][n] = __builtin_amdgcn_mfma_f32_32x32x16_bf16(av[m], bv[n],
                                                            acc[m][n], 0, 0, 0);
    __builtin_amdgcn_s_setprio(0);
    SCHB();
    if (t + 3 < NT)      { VM8(); }
    else if (t + 2 < NT) { VM4(); }
    else                 { VM0(); }
    BAR();
  }

#pragma unroll
  for (int m = 0; m < 4; ++m)
#pragma unroll
    for (int r = 0; r < 16; ++r) {
      const int row = wr * 128 + m * 32 + (r & 3) + 8 * (r >> 2) + 4 * hi;
      const int dst = e * G_ + mb * 256 + row;
      const int src = perm[dst];                 // expanded index t*K+k
      u16* orow = expo + (size_t)src * H_ + nb * 256 + wc * 64;
#pragma unroll
      for (int n = 0; n < 2; ++n)
        orow[n * 32 + l31] = f2bf(acc[m][n][r]);
    }
}

// ------------------------------------------------------------- combine -----
__global__ __launch_bounds__(256) void combine(const u16* __restrict__ expo,
                                               const int* __restrict__ ridx,
                                               const float* __restrict__ rw,
                                               float* __restrict__ out) {
  __shared__ float pr[K_];
  const int t = blockIdx.x;
  if (threadIdx.x < K_)
    pr[threadIdx.x] = rw[t * E_ + ridx[t * K_ + threadIdx.x]];
  __syncthreads();
  const int h0 = threadIdx.x * 8;
  float r[8] = {0.f, 0.f, 0.f, 0.f, 0.f, 0.f, 0.f, 0.f};
#pragma unroll
  for (int k = 0; k < K_; ++k) {
    const float p = pr[k];
    const u16x8 v = *(const u16x8*)&expo[((size_t)(t * K_ + k)) * H_ + h0];
#pragma unroll
    for (int j = 0; j < 8; ++j) r[j] += p * bf2f(v[j]);
  }
  float4 o0 = {r[0], r[1], r[2], r[3]};
  float4 o1 = {r[4], r[5], r[6], r[7]};
  *(float4*)&out[(size_t)t * H_ + h0]     = o0;
  *(float4*)&out[(size_t)t * H_ + h0 + 4] = o1;
}

// -------------------------------------------------------------- launch -----
extern "C" void kernel_launch(void* const* d_in, const int* in_sizes, int n_in,
                              void* d_out, int out_size, void* d_ws, size_t ws_size,
                              hipStream_t stream) {
  const float* hidden = (const float*)d_in[0];   // (T, H) f32
  const float* rw     = (const float*)d_in[1];   // (T, E) f32
  const int*   ridx   = (const int*)d_in[2];     // (T, K) i32
  const float* gup_f  = (const float*)d_in[3];   // (E, H, 2D) f32
  const float* dwn_f  = (const float*)d_in[4];   // (E, D, H) f32
  float* out = (float*)d_out;                    // (T, H) f32

  char* ws = (char*)d_ws;
  size_t off = 0;
  auto alloc = [&](size_t bytes) -> void* {
    void* p = ws + off;
    off += (bytes + 255) & ~(size_t)255;
    return p;
  };
  u16*   hid_bf = (u16*)alloc((size_t)T_ * H_ * 2);        //  16.8 MB
  u16*   gup_t  = (u16*)alloc((size_t)E_ * GU2 * H_ * 2);  // 201.3 MB (E,1536i,H)
  u16*   dwn_t  = (u16*)alloc((size_t)E_ * H_ * D_ * 2);   // 100.7 MB (E,H,D)
  u16*   act    = (u16*)alloc((size_t)M_ * D_ * 2);        //  50.3 MB
  u16*   expo   = (u16*)alloc((size_t)M_ * H_ * 2);        // 134.2 MB
  int*   perm   = (int*)alloc((size_t)M_ * 4);
  int*   gcnt   = (int*)alloc((size_t)E_ * 4);
  if (off > ws_size) return;   // workspace too small -> clean fail

  hipMemsetAsync(gcnt, 0, E_ * sizeof(int), stream);
  cvt_hidden<<<(T_ * H_ / 4) / 256, 256, 0, stream>>>(hidden, hid_bf);
  transpose_cvt<<<dim3(GU2 / 64, H_ / 64, E_), 256, 0, stream>>>(gup_f, gup_t, H_, GU2, 1);
  transpose_cvt<<<dim3(H_ / 64, D_ / 64, E_), 256, 0, stream>>>(dwn_f, dwn_t, D_, H_, 0);
  build_perm_fast<<<M_ / 256, 256, 0, stream>>>(ridx, perm, gcnt);
  gemm1_swiglu<<<6 * 4 * E_, 512, 0, stream>>>(hid_bf, gup_t, perm, act);
  gemm2_scatter<<<8 * 4 * E_, 512, 0, stream>>>(act, dwn_t, perm, expo);
  combine<<<T_, 256, 0, stream>>>(expo, ridx, rw, out);
}

// Round 6
// 541.238 us; speedup vs baseline: 1.2437x; 1.0425x over previous
//
#include <hip/hip_runtime.h>
#include <hip/hip_bf16.h>
#include <cstdint>

// Qwen3-VL-MoE text experts: permute -> grouped GEMM (gate_up) -> SwiGLU ->
// grouped GEMM (down) -> unpermute+combine.  bf16 MFMA path.
// R6: revert GEMMs to R4's 16x16 MFMA kernels (0 bank conflicts, proven);
// keep R5's build_perm_fast, fused combine, col-major-LDS transpose.

#define E_   32
#define H_   2048
#define D_   768
#define T_   4096
#define K_   8
#define M_   (T_ * K_)   // 32768 expanded rows
#define G_   (M_ / E_)   // 1024 rows per expert (balanced)
#define GU2  (2 * D_)    // 1536

typedef unsigned short u16;
typedef short bf16x8 __attribute__((ext_vector_type(8)));
typedef float f32x4 __attribute__((ext_vector_type(4)));
typedef unsigned short u16x2 __attribute__((ext_vector_type(2)));
typedef unsigned short u16x8 __attribute__((ext_vector_type(8)));

__device__ __forceinline__ u16 f2bf(float f) {          // RNE f32 -> bf16
  unsigned u = __float_as_uint(f);
  u += 0x7FFFu + ((u >> 16) & 1u);
  return (u16)(u >> 16);
}
__device__ __forceinline__ float bf2f(u16 v) {
  return __uint_as_float(((unsigned)v) << 16);
}

#define GLOAD16(g, l) __builtin_amdgcn_global_load_lds(                        \
    (const __attribute__((address_space(1))) void*)(g),                        \
    (__attribute__((address_space(3))) void*)(l), 16, 0, 0)

#define VM8()   asm volatile("s_waitcnt vmcnt(8)" ::: "memory")
#define VM4()   asm volatile("s_waitcnt vmcnt(4)" ::: "memory")
#define VM0()   asm volatile("s_waitcnt vmcnt(0)" ::: "memory")
#define LGKM0() asm volatile("s_waitcnt lgkmcnt(0)" ::: "memory")
#define SCHB()  __builtin_amdgcn_sched_barrier(0)
#define BAR()   __builtin_amdgcn_s_barrier()

// ---------------------------------------------------------------- prep ------
__global__ __launch_bounds__(256) void cvt_hidden(const float* __restrict__ in,
                                                  u16* __restrict__ out) {
  const int i = blockIdx.x * 256 + threadIdx.x;       // float4 groups
  const float4 v = ((const float4*)in)[i];
  u16x2 a; a.x = f2bf(v.x); a.y = f2bf(v.y);
  u16x2 b; b.x = f2bf(v.z); b.y = f2bf(v.w);
  *(u16x2*)&out[(size_t)i * 4]     = a;
  *(u16x2*)&out[(size_t)i * 4 + 2] = b;
}

// in: (B, R, C) f32  ->  out: (B, C, R) bf16, with optional gate/up
// 16-column interleave remap of the output row (mode 1: C==1536,
// gate j -> (j>>4)*32 + (j&15), up j -> (j>>4)*32 + 16 + (j&15)).
// Col-major LDS tile (pitch 72): f32x4 reads, b128 LDS reads, 16B stores.
__global__ __launch_bounds__(256) void transpose_cvt(const float* __restrict__ in,
                                                     u16* __restrict__ out,
                                                     int R, int C, int mode) {
  __shared__ u16 tl[64 * 72];        // tl[c*72 + r]
  const int b = blockIdx.z;
  const int c0 = blockIdx.x * 64, r0 = blockIdx.y * 64;
  const int tid = threadIdx.x;
  const float* ip = in + ((size_t)b * R + r0) * C + c0;
  const int rr4 = tid >> 4;          // 0..15
  const int cc4 = (tid & 15) * 4;    // 0,4,..,60
#pragma unroll
  for (int p = 0; p < 4; ++p) {
    const int r = p * 16 + rr4;
    const float4 v = *(const float4*)&ip[(size_t)r * C + cc4];
    tl[(cc4 + 0) * 72 + r] = f2bf(v.x);
    tl[(cc4 + 1) * 72 + r] = f2bf(v.y);
    tl[(cc4 + 2) * 72 + r] = f2bf(v.z);
    tl[(cc4 + 3) * 72 + r] = f2bf(v.w);
  }
  __syncthreads();
  const int rs = (tid & 7) * 8;      // 8-row strip start
#pragma unroll
  for (int q = 0; q < 2; ++q) {
    const int c = q * 32 + (tid >> 3);
    const int gc = c0 + c;
    int rr;
    if (mode == 1) {
      const int j = (gc < D_) ? gc : (gc - D_);
      rr = (j >> 4) * 32 + ((gc < D_) ? 0 : 16) + (j & 15);
    } else {
      rr = gc;
    }
    const u16x8 v = *(const u16x8*)&tl[c * 72 + rs];
    *(u16x8*)&out[((size_t)b * C + rr) * R + r0 + rs] = v;
  }
}

// ------------------------------------------------------------- routing -----
// Two-level atomic ranking: LDS histogram + one global atomicAdd per expert
// per block.  Order within an expert group is arbitrary; output values are
// independent of it (each row's dot products don't depend on its position).
__global__ __launch_bounds__(256) void build_perm_fast(const int* __restrict__ ridx,
                                                       int* __restrict__ perm,
                                                       int* __restrict__ gcnt) {
  __shared__ int lc[E_];
  __shared__ int lb[E_];
  const int tid = threadIdx.x;
  if (tid < E_) lc[tid] = 0;
  __syncthreads();
  const int i = blockIdx.x * 256 + tid;
  const int e = ridx[i];
  const int p = atomicAdd(&lc[e], 1);
  __syncthreads();
  if (tid < E_) lb[tid] = atomicAdd(&gcnt[tid], lc[tid]);
  __syncthreads();
  perm[e * G_ + lb[e] + p] = i;
}

// --------------------------------------------------------------- GEMM1 -----
// 256x256 tile, BK=32, 4-slot ring, depth-3 prefetch, 8 waves (2M x 4N).
__global__ __launch_bounds__(512, 2) void gemm1_swiglu(
    const u16* __restrict__ hid, const u16* __restrict__ gup,
    const int* __restrict__ perm, u16* __restrict__ act) {
  __shared__ u16 As[4][8192];   // 4 x 16 KiB
  __shared__ u16 Bs[4][8192];   // 4 x 16 KiB  (total 128 KiB)
  const int NT = H_ / 32;       // 64 K-tiles

  const int nwg = 6 * 4 * E_;   // 768, %8==0
  const int wid = (blockIdx.x % 8) * (nwg / 8) + blockIdx.x / 8;
  const int e = wid / 24;
  const int mb = (wid / 6) % 4;
  const int nb = wid % 6;

  const int tid = threadIdx.x;
  const int lane = tid & 63, w = tid >> 6;
  const int wr = w >> 2, wc = w & 3;           // 2 x 4 wave grid

  // staging sources: thread covers row (q*128 + tid>>2), 16B chunk (tid&3);
  // chunk pre-swizzled so ds_reads below are conflict-free (T2, rule #21).
  const int srow = tid >> 2, schunk = tid & 3;
  const u16* pA[2]; const u16* pB[2];
#pragma unroll
  for (int q = 0; q < 2; ++q) {
    const int r = q * 128 + srow;
    const int cg = (schunk ^ ((r >> 1) & 3)) * 8;
    const int token = perm[e * G_ + mb * 256 + r] >> 3;
    pA[q] = hid + (size_t)token * H_ + cg;
    pB[q] = gup + ((size_t)e * GU2 + nb * 256 + r) * H_ + cg;
  }

  // ds-read offsets (u16 units), swizzle matches staging pre-swizzle
  int aoff[8], boff[4];
  {
    const int l15 = lane & 15, hk = lane >> 4;
#pragma unroll
    for (int m = 0; m < 8; ++m) {
      const int rA = wr * 128 + m * 16 + l15;
      aoff[m] = rA * 32 + ((hk ^ ((rA >> 1) & 3)) * 8);
    }
#pragma unroll
    for (int n = 0; n < 4; ++n) {
      const int rB = wc * 64 + n * 16 + l15;
      boff[n] = rB * 32 + ((hk ^ ((rB >> 1) & 3)) * 8);
    }
  }

  f32x4 acc[8][4];
#pragma unroll
  for (int m = 0; m < 8; ++m)
#pragma unroll
    for (int n = 0; n < 4; ++n) acc[m][n] = (f32x4){0.f, 0.f, 0.f, 0.f};

  // prologue: stage tiles 0,1,2 into slots 0,1,2 (issue order = tile order)
  GLOAD16(pA[0], &As[0][tid * 8]);      GLOAD16(pA[1], &As[0][4096 + tid * 8]);
  GLOAD16(pB[0], &Bs[0][tid * 8]);      GLOAD16(pB[1], &Bs[0][4096 + tid * 8]);
  GLOAD16(pA[0] + 32, &As[1][tid * 8]); GLOAD16(pA[1] + 32, &As[1][4096 + tid * 8]);
  GLOAD16(pB[0] + 32, &Bs[1][tid * 8]); GLOAD16(pB[1] + 32, &Bs[1][4096 + tid * 8]);
  GLOAD16(pA[0] + 64, &As[2][tid * 8]); GLOAD16(pA[1] + 64, &As[2][4096 + tid * 8]);
  GLOAD16(pB[0] + 64, &Bs[2][tid * 8]); GLOAD16(pB[1] + 64, &Bs[2][4096 + tid * 8]);
  VM8(); BAR(); SCHB();                 // tile 0 landed; tiles 1,2 in flight

#pragma unroll 4
  for (int t = 0; t < NT; ++t) {
    const int slot = t & 3, ts = (t + 3) & 3;
    const bool st = (t + 3) < NT;
    const u16* Ab = As[slot]; const u16* Bb = Bs[slot];
    bf16x8 av[4], bv[4];
    // ---- phase A: read b[0..3]+a[0..3], stage A(t+3), 16 MFMA
#pragma unroll
    for (int n = 0; n < 4; ++n) bv[n] = *(const bf16x8*)&Bb[boff[n]];
#pragma unroll
    for (int m = 0; m < 4; ++m) av[m] = *(const bf16x8*)&Ab[aoff[m]];
    if (st) {
      GLOAD16(pA[0] + (t + 3) * 32, &As[ts][tid * 8]);
      GLOAD16(pA[1] + (t + 3) * 32, &As[ts][4096 + tid * 8]);
    }
    SCHB(); BAR(); LGKM0(); SCHB();
    __builtin_amdgcn_s_setprio(1);
#pragma unroll
    for (int m = 0; m < 4; ++m)
#pragma unroll
      for (int n = 0; n < 4; ++n)
        acc[m][n] = __builtin_amdgcn_mfma_f32_16x16x32_bf16(av[m], bv[n],
                                                            acc[m][n], 0, 0, 0);
    __builtin_amdgcn_s_setprio(0);
    SCHB(); BAR();
    // ---- phase B: read a[4..7], stage B(t+3), 16 MFMA
#pragma unroll
    for (int m = 0; m < 4; ++m) av[m] = *(const bf16x8*)&Ab[aoff[m + 4]];
    if (st) {
      GLOAD16(pB[0] + (t + 3) * 32, &Bs[ts][tid * 8]);
      GLOAD16(pB[1] + (t + 3) * 32, &Bs[ts][4096 + tid * 8]);
    }
    SCHB(); BAR(); LGKM0(); SCHB();
    __builtin_amdgcn_s_setprio(1);
#pragma unroll
    for (int m = 0; m < 4; ++m)
#pragma unroll
      for (int n = 0; n < 4; ++n)
        acc[m + 4][n] = __builtin_amdgcn_mfma_f32_16x16x32_bf16(av[m], bv[n],
                                                                acc[m + 4][n], 0, 0, 0);
    __builtin_amdgcn_s_setprio(0);
    SCHB();
    // ---- boundary: tile t+1 must be landed; up to 8 younger loads in flight
    if (t + 3 < NT)      { VM8(); }
    else if (t + 2 < NT) { VM4(); }
    else                 { VM0(); }
    BAR();
  }

  // epilogue: SwiGLU on paired (gate,up) fragments, store bf16 act
  const int lrow = (lane >> 4) * 4, lcol = lane & 15;
#pragma unroll
  for (int m = 0; m < 8; ++m)
#pragma unroll
    for (int p = 0; p < 2; ++p)
#pragma unroll
      for (int r = 0; r < 4; ++r) {
        const float g = acc[m][2 * p][r];
        const float u = acc[m][2 * p + 1][r];
        const float a_ = g / (1.f + __expf(-g)) * u;     // silu(g)*u
        const int row = mb * 256 + wr * 128 + m * 16 + lrow + r;
        const int dcol = (nb * 8 + wc * 2 + p) * 16 + lcol;
        act[((size_t)e * G_ + row) * D_ + dcol] = f2bf(a_);
      }
}

// --------------------------------------------------------------- GEMM2 -----
// Same structure, K=768; epilogue scatters rows to expanded order.
__global__ __launch_bounds__(512, 2) void gemm2_scatter(
    const u16* __restrict__ act, const u16* __restrict__ dwn,
    const int* __restrict__ perm, u16* __restrict__ expo) {
  __shared__ u16 As[4][8192];
  __shared__ u16 Bs[4][8192];
  const int NT = D_ / 32;       // 24 K-tiles

  const int nwg = 8 * 4 * E_;   // 1024, %8==0
  const int wid = (blockIdx.x % 8) * (nwg / 8) + blockIdx.x / 8;
  const int e = wid / 32;
  const int mb = (wid / 8) % 4;
  const int nb = wid % 8;

  const int tid = threadIdx.x;
  const int lane = tid & 63, w = tid >> 6;
  const int wr = w >> 2, wc = w & 3;

  const int srow = tid >> 2, schunk = tid & 3;
  const u16* pA[2]; const u16* pB[2];
#pragma unroll
  for (int q = 0; q < 2; ++q) {
    const int r = q * 128 + srow;
    const int cg = (schunk ^ ((r >> 1) & 3)) * 8;
    pA[q] = act + ((size_t)e * G_ + mb * 256 + r) * D_ + cg;
    pB[q] = dwn + ((size_t)e * H_ + nb * 256 + r) * D_ + cg;
  }

  int aoff[8], boff[4];
  {
    const int l15 = lane & 15, hk = lane >> 4;
#pragma unroll
    for (int m = 0; m < 8; ++m) {
      const int rA = wr * 128 + m * 16 + l15;
      aoff[m] = rA * 32 + ((hk ^ ((rA >> 1) & 3)) * 8);
    }
#pragma unroll
    for (int n = 0; n < 4; ++n) {
      const int rB = wc * 64 + n * 16 + l15;
      boff[n] = rB * 32 + ((hk ^ ((rB >> 1) & 3)) * 8);
    }
  }

  f32x4 acc[8][4];
#pragma unroll
  for (int m = 0; m < 8; ++m)
#pragma unroll
    for (int n = 0; n < 4; ++n) acc[m][n] = (f32x4){0.f, 0.f, 0.f, 0.f};

  GLOAD16(pA[0], &As[0][tid * 8]);      GLOAD16(pA[1], &As[0][4096 + tid * 8]);
  GLOAD16(pB[0], &Bs[0][tid * 8]);      GLOAD16(pB[1], &Bs[0][4096 + tid * 8]);
  GLOAD16(pA[0] + 32, &As[1][tid * 8]); GLOAD16(pA[1] + 32, &As[1][4096 + tid * 8]);
  GLOAD16(pB[0] + 32, &Bs[1][tid * 8]); GLOAD16(pB[1] + 32, &Bs[1][4096 + tid * 8]);
  GLOAD16(pA[0] + 64, &As[2][tid * 8]); GLOAD16(pA[1] + 64, &As[2][4096 + tid * 8]);
  GLOAD16(pB[0] + 64, &Bs[2][tid * 8]); GLOAD16(pB[1] + 64, &Bs[2][4096 + tid * 8]);
  VM8(); BAR(); SCHB();

#pragma unroll 4
  for (int t = 0; t < NT; ++t) {
    const int slot = t & 3, ts = (t + 3) & 3;
    const bool st = (t + 3) < NT;
    const u16* Ab = As[slot]; const u16* Bb = Bs[slot];
    bf16x8 av[4], bv[4];
#pragma unroll
    for (int n = 0; n < 4; ++n) bv[n] = *(const bf16x8*)&Bb[boff[n]];
#pragma unroll
    for (int m = 0; m < 4; ++m) av[m] = *(const bf16x8*)&Ab[aoff[m]];
    if (st) {
      GLOAD16(pA[0] + (t + 3) * 32, &As[ts][tid * 8]);
      GLOAD16(pA[1] + (t + 3) * 32, &As[ts][4096 + tid * 8]);
    }
    SCHB(); BAR(); LGKM0(); SCHB();
    __builtin_amdgcn_s_setprio(1);
#pragma unroll
    for (int m = 0; m < 4; ++m)
#pragma unroll
      for (int n = 0; n < 4; ++n)
        acc[m][n] = __builtin_amdgcn_mfma_f32_16x16x32_bf16(av[m], bv[n],
                                                            acc[m][n], 0, 0, 0);
    __builtin_amdgcn_s_setprio(0);
    SCHB(); BAR();
#pragma unroll
    for (int m = 0; m < 4; ++m) av[m] = *(const bf16x8*)&Ab[aoff[m + 4]];
    if (st) {
      GLOAD16(pB[0] + (t + 3) * 32, &Bs[ts][tid * 8]);
      GLOAD16(pB[1] + (t + 3) * 32, &Bs[ts][4096 + tid * 8]);
    }
    SCHB(); BAR(); LGKM0(); SCHB();
    __builtin_amdgcn_s_setprio(1);
#pragma unroll
    for (int m = 0; m < 4; ++m)
#pragma unroll
      for (int n = 0; n < 4; ++n)
        acc[m + 4][n] = __builtin_amdgcn_mfma_f32_16x16x32_bf16(av[m], bv[n],
                                                                acc[m + 4][n], 0, 0, 0);
    __builtin_amdgcn_s_setprio(0);
    SCHB();
    if (t + 3 < NT)      { VM8(); }
    else if (t + 2 < NT) { VM4(); }
    else                 { VM0(); }
    BAR();
  }

  const int lrow = (lane >> 4) * 4, lcol = lane & 15;
#pragma unroll
  for (int m = 0; m < 8; ++m)
#pragma unroll
    for (int r = 0; r < 4; ++r) {
      const int dst = e * G_ + mb * 256 + wr * 128 + m * 16 + lrow + r;
      const int src = perm[dst];                 // expanded index t*K+k
      u16* orow = expo + (size_t)src * H_ + nb * 256 + wc * 64;
#pragma unroll
      for (int n = 0; n < 4; ++n)
        orow[n * 16 + lcol] = f2bf(acc[m][n][r]);
    }
}

// ------------------------------------------------------------- combine -----
__global__ __launch_bounds__(256) void combine(const u16* __restrict__ expo,
                                               const int* __restrict__ ridx,
                                               const float* __restrict__ rw,
                                               float* __restrict__ out) {
  __shared__ float pr[K_];
  const int t = blockIdx.x;
  if (threadIdx.x < K_)
    pr[threadIdx.x] = rw[t * E_ + ridx[t * K_ + threadIdx.x]];
  __syncthreads();
  const int h0 = threadIdx.x * 8;
  float r[8] = {0.f, 0.f, 0.f, 0.f, 0.f, 0.f, 0.f, 0.f};
#pragma unroll
  for (int k = 0; k < K_; ++k) {
    const float p = pr[k];
    const u16x8 v = *(const u16x8*)&expo[((size_t)(t * K_ + k)) * H_ + h0];
#pragma unroll
    for (int j = 0; j < 8; ++j) r[j] += p * bf2f(v[j]);
  }
  float4 o0 = {r[0], r[1], r[2], r[3]};
  float4 o1 = {r[4], r[5], r[6], r[7]};
  *(float4*)&out[(size_t)t * H_ + h0]     = o0;
  *(float4*)&out[(size_t)t * H_ + h0 + 4] = o1;
}

// -------------------------------------------------------------- launch -----
extern "C" void kernel_launch(void* const* d_in, const int* in_sizes, int n_in,
                              void* d_out, int out_size, void* d_ws, size_t ws_size,
                              hipStream_t stream) {
  const float* hidden = (const float*)d_in[0];   // (T, H) f32
  const float* rw     = (const float*)d_in[1];   // (T, E) f32
  const int*   ridx   = (const int*)d_in[2];     // (T, K) i32
  const float* gup_f  = (const float*)d_in[3];   // (E, H, 2D) f32
  const float* dwn_f  = (const float*)d_in[4];   // (E, D, H) f32
  float* out = (float*)d_out;                    // (T, H) f32

  char* ws = (char*)d_ws;
  size_t off = 0;
  auto alloc = [&](size_t bytes) -> void* {
    void* p = ws + off;
    off += (bytes + 255) & ~(size_t)255;
    return p;
  };
  u16*   hid_bf = (u16*)alloc((size_t)T_ * H_ * 2);        //  16.8 MB
  u16*   gup_t  = (u16*)alloc((size_t)E_ * GU2 * H_ * 2);  // 201.3 MB (E,1536i,H)
  u16*   dwn_t  = (u16*)alloc((size_t)E_ * H_ * D_ * 2);   // 100.7 MB (E,H,D)
  u16*   act    = (u16*)alloc((size_t)M_ * D_ * 2);        //  50.3 MB
  u16*   expo   = (u16*)alloc((size_t)M_ * H_ * 2);        // 134.2 MB
  int*   perm   = (int*)alloc((size_t)M_ * 4);
  int*   gcnt   = (int*)alloc((size_t)E_ * 4);
  if (off > ws_size) return;   // workspace too small -> clean fail

  hipMemsetAsync(gcnt, 0, E_ * sizeof(int), stream);
  cvt_hidden<<<(T_ * H_ / 4) / 256, 256, 0, stream>>>(hidden, hid_bf);
  transpose_cvt<<<dim3(GU2 / 64, H_ / 64, E_), 256, 0, stream>>>(gup_f, gup_t, H_, GU2, 1);
  transpose_cvt<<<dim3(H_ / 64, D_ / 64, E_), 256, 0, stream>>>(dwn_f, dwn_t, D_, H_, 0);
  build_perm_fast<<<M_ / 256, 256, 0, stream>>>(ridx, perm, gcnt);
  gemm1_swiglu<<<6 * 4 * E_, 512, 0, stream>>>(hid_bf, gup_t, perm, act);
  gemm2_scatter<<<8 * 4 * E_, 512, 0, stream>>>(act, dwn_t, perm, expo);
  combine<<<T_, 256, 0, stream>>>(expo, ridx, rw, out);
}